// Round 1
// baseline (659.710 us; speedup 1.0000x reference)
//
#include <hip/hip_runtime.h>

#define N_N 100000
#define N_E 1600000
#define N_G 5000
#define HID 256
#define IND 14

#define NBUK 391      // buckets: dst>>8, 256 nodes each (391*256 = 100096)
#define CAP 5120      // static per-bucket capacity (E[cnt]=4096, sigma~64; +16 sigma)
#define CH3 8192      // edges per binning block (512 threads)
#define NFB 196       // ceil(N_E/CH3)

typedef __bf16 bf16x8 __attribute__((ext_vector_type(8)));
typedef float f32x4 __attribute__((ext_vector_type(4)));
typedef unsigned short u16;
typedef unsigned int u32;

// ---- workspace layout (units of 4 bytes) ----
constexpr size_t OFF_OUTS  = 0;          // float[5120]   (zeroed)
constexpr size_t OFF_GCUR  = 5120;       // int[391*16]   (zeroed, 64B-padded cursors)
constexpr size_t ZERO_END  = 11520;
constexpr size_t ZERO_BYTES = ZERO_END * 4;
constexpr size_t OFF_GCNT  = 11520;      // float[5120] (fully written)
constexpr size_t OFF_ROWP  = 16640;      // int[100096]
constexpr size_t OFF_DEG   = 116736;     // int[100096]
constexpr size_t OFF_EBUF  = 216832;     // u32[391*5120]; dead after k_sort -> reused as zb (bf16[100000*32] = 6.4MB < 8MB)
constexpr size_t OFF_CSRC  = 2218752;    // int[391*5120]
constexpr size_t OFF_H1B   = 4220672;    // bf16[100096*256] -> ends 17032960
constexpr size_t OFF_WCAT  = 17032960;   // bf16[256*512]    -> ends 17098496
constexpr size_t OFF_XP    = 17098496;   // bf16[N*16]       -> ends 17898496
constexpr size_t OFF_MEAN1B= 17898496;   // bf16[100096*256] -> ends 30710784
constexpr size_t OFF_W1CAT = 30710784;   // bf16[256*32]     -> ends 30714880
// end = 30714880 floats ~= 123 MB

__device__ __forceinline__ u32 f2b(float f) {
    u32 u = __float_as_uint(f);
    u32 r = u + 0x7FFFu + ((u >> 16) & 1u);
    return r >> 16;
}

#define ADD8(acc, v) do { \
    acc[0] += __uint_as_float(v.x << 16); \
    acc[1] += __uint_as_float(v.x & 0xFFFF0000u); \
    acc[2] += __uint_as_float(v.y << 16); \
    acc[3] += __uint_as_float(v.y & 0xFFFF0000u); \
    acc[4] += __uint_as_float(v.z << 16); \
    acc[5] += __uint_as_float(v.z & 0xFFFF0000u); \
    acc[6] += __uint_as_float(v.w << 16); \
    acc[7] += __uint_as_float(v.w & 0xFFFF0000u); \
} while (0)

// ---- MERGED binning + prep; scan via wave-shuffle (2 barriers vs 18) ----
#define PACK_N (N_N * 16)
#define WCAT_N (256 * 512)
#define W1CAT_N (256 * 32)
#define PREP_TOT (PACK_N + WCAT_N + W1CAT_N + N_G)
#define PREP_BLKS ((PREP_TOT + 511) / 512)      // 3407
__global__ __launch_bounds__(512) void k_bfill_prep(const int* __restrict__ ei, int* __restrict__ gcur,
                                                    u32* __restrict__ ebuf,
                                                    const float* __restrict__ x, const float* __restrict__ pos,
                                                    const int* __restrict__ batch,
                                                    const float* __restrict__ W2l, const float* __restrict__ W2r,
                                                    const float* __restrict__ W1l, const float* __restrict__ W1r,
                                                    u16* __restrict__ xpb, float* __restrict__ gcnt,
                                                    u16* __restrict__ wcat, u16* __restrict__ w1cat) {
    __shared__ int hist[NBUK];
    __shared__ int lcur[NBUK];
    __shared__ int gbase[NBUK];
    __shared__ int wsum[8];
    __shared__ u32 stage[CH3];
    __shared__ u16 bstage[CH3];
    int t = threadIdx.x;
    if (blockIdx.x >= NFB) {
        int idx = (blockIdx.x - NFB) * 512 + t;
        if (idx < PACK_N) {
            int n = idx >> 4, f = idx & 15;
            float v = 0.f;
            if (f < 11) v = x[n * 11 + f];
            else if (f < 14) v = pos[n * 3 + (f - 11)];
            xpb[idx] = (u16)f2b(v);
        } else if (idx < PACK_N + WCAT_N) {
            int i2 = idx - PACK_N;
            int n = i2 >> 9, k = i2 & 511;
            float v = (k < 256) ? W2l[k * HID + n] : W2r[(k - 256) * HID + n];
            wcat[(size_t)n * 512 + k] = (u16)f2b(v);
        } else if (idx < PACK_N + WCAT_N + W1CAT_N) {
            int i2 = idx - PACK_N - WCAT_N;
            int n = i2 >> 5, k = i2 & 31;
            float v = 0.f;
            if (k < IND) v = W1l[k * HID + n];
            else if (k >= 16 && k < 16 + IND) v = W1r[(k - 16) * HID + n];
            w1cat[(size_t)n * 32 + k] = (u16)f2b(v);
        } else if (idx < PREP_TOT) {
            int g = idx - PACK_N - WCAT_N - W1CAT_N;
            int lo = 0, hi = N_N;
            while (lo < hi) { int mid = (lo + hi) >> 1; if (batch[mid] < g) lo = mid + 1; else hi = mid; }
            int lo2 = lo, hi2 = N_N;
            while (lo2 < hi2) { int mid = (lo2 + hi2) >> 1; if (batch[mid] < g + 1) lo2 = mid + 1; else hi2 = mid; }
            gcnt[g] = (float)(lo2 - lo);
        }
        return;
    }
    int lane = t & 63, wv = t >> 6;
    int base = blockIdx.x * CH3;
    for (int i = t; i < NBUK; i += 512) hist[i] = 0;
    __syncthreads();
#pragma unroll
    for (int i = 0; i < 16; i++) {
        int e = base + i * 512 + t;
        if (e < N_E) atomicAdd(&hist[ei[N_E + e] >> 8], 1);
    }
    __syncthreads();
    // wave-shuffle inclusive scan of hist over 512 lanes
    int v = (t < NBUK) ? hist[t] : 0;
    int inc = v;
#pragma unroll
    for (int off = 1; off < 64; off <<= 1) {
        int u = __shfl_up(inc, off, 64);
        if (lane >= off) inc += u;
    }
    if (lane == 63) wsum[wv] = inc;
    __syncthreads();
    int pre = 0;
    for (int i = 0; i < wv; i++) pre += wsum[i];
    int inclusive = inc + pre;
    int excl = inclusive - v;                 // exclusive base within stage (reg-saved)
    if (t < NBUK) lcur[t] = excl;
    int blockcnt = 0;
#pragma unroll
    for (int i = 0; i < 8; i++) blockcnt += wsum[i];
    __syncthreads();
#pragma unroll
    for (int i = 0; i < 16; i++) {
        int e = base + i * 512 + t;
        if (e < N_E) {
            int d = ei[N_E + e];
            int s = ei[e];
            int b = d >> 8;
            int p = atomicAdd(&lcur[b], 1);
            stage[p] = (u32)s | ((u32)(d & 255) << 17);
            bstage[p] = (u16)b;
        }
    }
    __syncthreads();
    if (t < NBUK) {
        int c = hist[t];
        int o = c ? atomicAdd(&gcur[t * 16], c) : 0;
        gbase[t] = t * CAP + o - excl;        // so global = gbase[b] + p
    }
    __syncthreads();
#pragma unroll
    for (int i = 0; i < 16; i++) {
        int p = i * 512 + t;
        if (p < blockcnt) {
            int b = bstage[p];
            ebuf[gbase[b] + p] = stage[p];
        }
    }
}

// ---- per-bucket counting sort (static bases; wave-shuffle scan, 4 barriers) ----
__global__ __launch_bounds__(256) void k_sort(const u32* __restrict__ ebuf, const int* __restrict__ gcur,
                                              int* __restrict__ csrc, int* __restrict__ deg,
                                              int* __restrict__ rowp) {
    __shared__ int degL[256];
    __shared__ int curL[256];
    __shared__ int wsum[4];
    int t = threadIdx.x;
    int lane = t & 63, wv = t >> 6;
    int b = blockIdx.x;
    int bs = b * CAP;
    int be = bs + gcur[b * 16];
    degL[t] = 0;
    __syncthreads();
    for (int e = bs + t; e < be; e += 256)
        atomicAdd(&degL[ebuf[e] >> 17], 1);
    __syncthreads();
    int myDeg = degL[t];
    int inc = myDeg;
#pragma unroll
    for (int off = 1; off < 64; off <<= 1) {
        int u = __shfl_up(inc, off, 64);
        if (lane >= off) inc += u;
    }
    if (lane == 63) wsum[wv] = inc;
    __syncthreads();
    int pre = 0;
    for (int i = 0; i < wv; i++) pre += wsum[i];
    int excl = inc + pre - myDeg;
    int node = (b << 8) + t;       // < 100096; deg=0 for node >= N_N
    deg[node] = myDeg;
    rowp[node] = bs + excl;
    curL[t] = bs + excl;
    __syncthreads();
    for (int e = bs + t; e < be; e += 256) {
        u32 w = ebuf[e];
        int p = atomicAdd(&curL[w >> 17], 1);
        csrc[p] = (int)(w & 0x1FFFFu);
    }
}

// ---- layer 1: gather (8 lanes/edge, unroll-2) + MFMA matmul; now also persists
// the 32-wide z-rows (As) to zb so k_agg can recompute h1 from a 64B gather ----
__global__ __launch_bounds__(256) void k_layer1(const u16* __restrict__ xpb,
                                                const int* __restrict__ rowp, const int* __restrict__ deg,
                                                const int* __restrict__ csrc,
                                                const u16* __restrict__ w1cat, const float* __restrict__ b1,
                                                u16* __restrict__ h1b, u16* __restrict__ zb) {
    __shared__ u16 As[16][32];       // [node][k]: k0..15 = mean(xp) (14,15=0), k16..31 = own row
    __shared__ u16 outS[16][256];    // D staging for coalesced writeout
    int tid = threadIdx.x;
    int wave = tid >> 6, lane = tid & 63;
    int fp = lane & 7;          // feature pair 0..7
    int eg = lane >> 3;         // edge group 0..7
#pragma unroll
    for (int nn = 0; nn < 4; nn++) {
        int s = wave * 4 + nn;
        int node = blockIdx.x * 16 + s;     // grid covers exactly N_N
        int st = rowp[node], dg = deg[node];
        int end = st + dg;
        float a0 = 0.f, a1 = 0.f, b0 = 0.f, b1v = 0.f;
        int e = st + eg;
        for (; e + 8 < end; e += 16) {      // unroll-2: both csrc loads independent
            int nb1 = csrc[e];
            int nb2 = csrc[e + 8];
            u32 v1 = *(const u32*)(xpb + (size_t)nb1 * 16 + fp * 2);
            u32 v2 = *(const u32*)(xpb + (size_t)nb2 * 16 + fp * 2);
            a0 += __uint_as_float(v1 << 16);
            a1 += __uint_as_float(v1 & 0xFFFF0000u);
            b0 += __uint_as_float(v2 << 16);
            b1v += __uint_as_float(v2 & 0xFFFF0000u);
        }
        if (e < end) {
            int nb = csrc[e];
            u32 v = *(const u32*)(xpb + (size_t)nb * 16 + fp * 2);
            a0 += __uint_as_float(v << 16);
            a1 += __uint_as_float(v & 0xFFFF0000u);
        }
        a0 += b0; a1 += b1v;
        if (eg == 1) {   // own row is already bf16: copy pair directly (k 16..31)
            *(u32*)&As[s][16 + fp * 2] = *(const u32*)(xpb + (size_t)node * 16 + fp * 2);
        }
#pragma unroll
        for (int off = 32; off >= 8; off >>= 1) {
            a0 += __shfl_down(a0, off);
            a1 += __shfl_down(a1, off);
        }
        if (eg == 0) {
            float inv = 1.f / (float)max(dg, 1);
            *(u32*)&As[s][fp * 2] = f2b(a0 * inv) | (f2b(a1 * inv) << 16);
        }
    }
    __syncthreads();
    // persist z-rows: thread t -> node t>>4, u32 pair t&15 (coalesced 1KB/block)
    {
        int s = tid >> 4, kp = tid & 15;
        *(u32*)(zb + (size_t)(blockIdx.x * 16 + s) * 32 + kp * 2) = *(const u32*)&As[s][kp * 2];
    }
    // ---- MFMA phase: wave w covers output feats [w*64, w*64+64) as 4 16x16 tiles ----
    int quad = lane >> 4, m16 = lane & 15;
    bf16x8 afrag = *(const bf16x8*)&As[m16][quad * 8];
#pragma unroll
    for (int u = 0; u < 4; u++) {
        int feat = wave * 64 + u * 16 + m16;
        bf16x8 bfrag = *(const bf16x8*)(w1cat + (size_t)feat * 32 + quad * 8);
        f32x4 d = {0.f, 0.f, 0.f, 0.f};
        d = __builtin_amdgcn_mfma_f32_16x16x32_bf16(afrag, bfrag, d, 0, 0, 0);
        float bj = b1[feat];
#pragma unroll
        for (int i = 0; i < 4; i++) {
            int row = quad * 4 + i;          // node within tile
            outS[row][feat] = (u16)f2b(fmaxf(d[i] + bj, 0.f));
        }
    }
    __syncthreads();
    // ---- coalesced writeout: thread t -> node t>>4, 32B chunk t&15 ----
    int r = tid >> 4, c = tid & 15;
    uint4* dst = (uint4*)(h1b + ((size_t)(blockIdx.x * 16 + r)) * HID + c * 16);
    dst[0] = *(const uint4*)&outS[r][c * 16];
    dst[1] = *(const uint4*)&outS[r][c * 16 + 8];
}

// ---- layer-2 mean aggregation, RECOMPUTE form: instead of gathering 512B h1
// rows (51MB working set -> pinned at the ~3.9 TB/s L2-miss wall), gather the
// 64B z-rows (6.4MB working set -> L2/LLC resident) and recompute
// h1[s] = relu(z[s] @ W1cat + b1) per edge with the same MFMA as layer 1,
// summing the relu'd rows in f32. 1 wave/node; 16 edges per A-tile. ----
__global__ __launch_bounds__(256) void k_agg(const u16* __restrict__ zb, const int* __restrict__ rowp,
                                             const int* __restrict__ deg, const int* __restrict__ csrc,
                                             const u16* __restrict__ w1cat, const float* __restrict__ b1,
                                             u16* __restrict__ mean1b) {
    __shared__ u16 outW[4][256];     // per-wave writeout staging
    int tid = threadIdx.x;
    int wv = tid >> 6, lane = tid & 63;
    int quad = lane >> 4, m16 = lane & 15;
    int node = blockIdx.x * 4 + wv;  // grid covers exactly N_N
    int st = rowp[node], dg = deg[node];
    int end = st + dg;

    // hoist B-frags (w1cat, 16KB shared by all waves -> L2 broadcast) + bias
    bf16x8 bfrag[16];
    float bb[16];
#pragma unroll
    for (int u = 0; u < 16; u++) {
        bfrag[u] = *(const bf16x8*)(w1cat + (size_t)(u * 16 + m16) * 32 + quad * 8);
        bb[u] = b1[u * 16 + m16];
    }
    float acc[16] = {};              // feat col = u*16+m16, partial over rows quad*4..+3
    for (int cb = 0; cb < dg; cb += 16) {
        int e = st + cb + m16;
        int nb = (e < end) ? csrc[e] : csrc[st];   // clamp tail to a valid row (masked below)
        bf16x8 afrag = *(const bf16x8*)(zb + (size_t)nb * 32 + quad * 8);
        float mk[4];
#pragma unroll
        for (int i = 0; i < 4; i++)
            mk[i] = (cb + quad * 4 + i < dg) ? 1.f : 0.f;
#pragma unroll
        for (int u = 0; u < 16; u++) {
            f32x4 d = {0.f, 0.f, 0.f, 0.f};
            d = __builtin_amdgcn_mfma_f32_16x16x32_bf16(afrag, bfrag[u], d, 0, 0, 0);
#pragma unroll
            for (int i = 0; i < 4; i++)
                acc[u] = fmaf(mk[i], fmaxf(d[i] + bb[u], 0.f), acc[u]);
        }
    }
    float inv = 1.f / (float)max(dg, 1);
#pragma unroll
    for (int u = 0; u < 16; u++) {
        float a = acc[u];
        a += __shfl_down(a, 32);     // quads {0,1}+{2,3}
        a += __shfl_down(a, 16);     // + quad 1
        if (quad == 0) outW[wv][u * 16 + m16] = (u16)f2b(a * inv);
    }
    // same-wave LDS dependency: compiler orders via lgkmcnt; no barrier needed
    if (lane < 32)
        *(uint4*)(mean1b + (size_t)node * HID + (size_t)lane * 8) = *(const uint4*)&outW[wv][lane * 8];
}

// ---- layer 2 (BM=128, Bs double-kt — ~24 us): direct-global A-frags + register
// prefetch; fused relu + Wout-dot + pool atomic ----
__global__ __launch_bounds__(256, 2) void k_layer2(const u16* __restrict__ mean1b, const u16* __restrict__ h1b,
                                                   const u16* __restrict__ wcat, const float* __restrict__ b2,
                                                   const int* __restrict__ batch, const float* __restrict__ Wout,
                                                   float* __restrict__ outsum) {
    __shared__ u16 Bs[2][256][40];
    int tid = threadIdx.x;
    int wave = tid >> 6, lane = tid & 63;
    int quad = lane >> 4, m16 = lane & 15;
    int bm = blockIdx.x;
    const size_t r0 = (size_t)(bm * 128 + wave * 32 + m16) * HID + quad * 8;
    const size_t r1 = r0 + 16 * HID;
    f32x4 acc[2][16] = {};
    uint4 a0 = *(const uint4*)(mean1b + r0);
    uint4 a1 = *(const uint4*)(mean1b + r1);
    for (int kt2 = 0; kt2 < 8; kt2++) {
        __syncthreads();
#pragma unroll
        for (int h = 0; h < 2; h++) {
            int kt = kt2 * 2 + h;
#pragma unroll
            for (int i = 0; i < 4; i++) {
                int cidx = tid + 256 * i;
                int n = cidx >> 2, kc = cidx & 3;
                *(uint4*)&Bs[h][n][kc * 8] =
                    *(const uint4*)(wcat + (size_t)n * 512 + kt * 32 + kc * 8);
            }
        }
        __syncthreads();
#pragma unroll
        for (int h = 0; h < 2; h++) {
            int kt = kt2 * 2 + h;
            uint4 cur0 = a0, cur1 = a1;
            if (kt < 15) {
                int kg = (kt + 1) * 32;
                const u16* An = (kg < 256) ? (mean1b + kg) : (h1b + (kg - 256));
                a0 = *(const uint4*)(An + r0);
                a1 = *(const uint4*)(An + r1);
            }
            bf16x8 af0 = __builtin_bit_cast(bf16x8, cur0);
            bf16x8 af1 = __builtin_bit_cast(bf16x8, cur1);
#pragma unroll
            for (int u = 0; u < 16; u++) {
                bf16x8 bf = *(const bf16x8*)&Bs[h][u * 16 + m16][quad * 8];
                acc[0][u] = __builtin_amdgcn_mfma_f32_16x16x32_bf16(af0, bf, acc[0][u], 0, 0, 0);
                acc[1][u] = __builtin_amdgcn_mfma_f32_16x16x32_bf16(af1, bf, acc[1][u], 0, 0, 0);
            }
        }
    }
    float wo[16], bb[16];
#pragma unroll
    for (int u = 0; u < 16; u++) { int col = u * 16 + m16; wo[u] = Wout[col]; bb[u] = b2[col]; }
#pragma unroll
    for (int t = 0; t < 2; t++) {
#pragma unroll
        for (int i = 0; i < 4; i++) {
            float p = 0.f;
#pragma unroll
            for (int u = 0; u < 16; u++)
                p = fmaf(fmaxf(acc[t][u][i] + bb[u], 0.f), wo[u], p);
#pragma unroll
            for (int off = 8; off > 0; off >>= 1) p += __shfl_down(p, off, 16);
            int row = bm * 128 + wave * 32 + t * 16 + quad * 4 + i;
            if (m16 == 0 && row < N_N) atomicAdd(&outsum[batch[row]], p);
        }
    }
}

// ---- output head ----
__global__ __launch_bounds__(256) void k_out(const float* __restrict__ outsum, const float* __restrict__ gcnt,
                                             const float* __restrict__ bout, float* __restrict__ out) {
    int g = blockIdx.x * 256 + threadIdx.x;
    if (g < N_G) out[g] = outsum[g] / fmaxf(gcnt[g], 1.f) + bout[0];
}

extern "C" void kernel_launch(void* const* d_in, const int* in_sizes, int n_in,
                              void* d_out, int out_size, void* d_ws, size_t ws_size,
                              hipStream_t stream) {
    const float* x    = (const float*)d_in[0];
    const float* pos  = (const float*)d_in[1];
    const int*   ei   = (const int*)d_in[2];
    const int*   batch= (const int*)d_in[3];
    const float* W1l  = (const float*)d_in[4];
    const float* b1   = (const float*)d_in[5];
    const float* W1r  = (const float*)d_in[6];
    const float* W2l  = (const float*)d_in[7];
    const float* b2   = (const float*)d_in[8];
    const float* W2r  = (const float*)d_in[9];
    const float* Wout = (const float*)d_in[10];
    const float* bout = (const float*)d_in[11];
    float* out = (float*)d_out;
    float* ws  = (float*)d_ws;

    float* outs  = ws + OFF_OUTS;
    int*   gcur  = (int*)(ws + OFF_GCUR);
    float* gcnt  = ws + OFF_GCNT;
    int*   rowp  = (int*)(ws + OFF_ROWP);
    int*   deg   = (int*)(ws + OFF_DEG);
    u32*   ebuf  = (u32*)(ws + OFF_EBUF);
    int*   csrc  = (int*)(ws + OFF_CSRC);
    u16*   h1b   = (u16*)(ws + OFF_H1B);
    u16*   wcat  = (u16*)(ws + OFF_WCAT);
    u16*   xpb   = (u16*)(ws + OFF_XP);
    u16*   mean1b= (u16*)(ws + OFF_MEAN1B);
    u16*   w1cat = (u16*)(ws + OFF_W1CAT);
    u16*   zb    = (u16*)ebuf;      // ebuf is dead after k_sort; reuse for z-rows

    hipMemsetAsync(d_ws, 0, ZERO_BYTES, stream);
    k_bfill_prep<<<NFB + PREP_BLKS, 512, 0, stream>>>(
        ei, gcur, ebuf, x, pos, batch, W2l, W2r, W1l, W1r, xpb, gcnt, wcat, w1cat);
    k_sort  <<<NBUK, 256, 0, stream>>>(ebuf, gcur, csrc, deg, rowp);
    k_layer1<<<N_N / 16, 256, 0, stream>>>(xpb, rowp, deg, csrc, w1cat, b1, h1b, zb);
    k_agg   <<<N_N / 4, 256, 0, stream>>>(zb, rowp, deg, csrc, w1cat, b1, mean1b);
    k_layer2<<<(N_N + 127) / 128, 256, 0, stream>>>(mean1b, h1b, wcat, b2, batch, Wout, outs);
    k_out   <<<(N_G + 255) / 256, 256, 0, stream>>>(outs, gcnt, bout, out);
}

// Round 2
// 586.537 us; speedup vs baseline: 1.1248x; 1.1248x over previous
//
#include <hip/hip_runtime.h>

#define N_N 100000
#define N_E 1600000
#define N_G 5000
#define HID 256
#define IND 14

#define NBUK 391      // buckets: dst>>8, 256 nodes each (391*256 = 100096)
#define CAP 5120      // static per-bucket capacity (E[cnt]=4096, sigma~64; +16 sigma)
#define CH3 8192      // edges per binning block (512 threads)
#define NFB 196       // ceil(N_E/CH3)

typedef __bf16 bf16x8 __attribute__((ext_vector_type(8)));
typedef float f32x4 __attribute__((ext_vector_type(4)));
typedef unsigned short u16;
typedef unsigned int u32;

// ---- workspace layout (units of 4 bytes) ----
constexpr size_t OFF_OUTS  = 0;          // float[5120]   (zeroed)
constexpr size_t OFF_GCUR  = 5120;       // int[391*16]   (zeroed, 64B-padded cursors)
constexpr size_t ZERO_END  = 11520;
constexpr size_t ZERO_BYTES = ZERO_END * 4;
constexpr size_t OFF_GCNT  = 11520;      // float[5120] (fully written)
constexpr size_t OFF_ROWP  = 16640;      // int[100096]
constexpr size_t OFF_DEG   = 116736;     // int[100096]
constexpr size_t OFF_EBUF  = 216832;     // u32[391*5120]; dead after k_sort -> reused as zb (bf16[(100000+1)*32] = 6.4MB < 8MB)
constexpr size_t OFF_CSRC  = 2218752;    // int[391*5120]
constexpr size_t OFF_H1B   = 4220672;    // bf16[100096*256] -> ends 17032960
constexpr size_t OFF_WCAT  = 17032960;   // bf16[256*512]    -> ends 17098496
constexpr size_t OFF_XP    = 17098496;   // bf16[N*16]       -> ends 17898496
constexpr size_t OFF_MEAN1B= 17898496;   // bf16[100096*256] -> ends 30710784
constexpr size_t OFF_W1CAT = 30710784;   // bf16[256*32]     -> ends 30714880
// end = 30714880 floats ~= 123 MB

#define ZROW N_N      // all-zero z-row for branchless chunk tails
#define NPW 8         // nodes per wave in k_agg

__device__ __forceinline__ u32 f2b(float f) {
    u32 u = __float_as_uint(f);
    u32 r = u + 0x7FFFu + ((u >> 16) & 1u);
    return r >> 16;
}

#define ADD8(acc, v) do { \
    acc[0] += __uint_as_float(v.x << 16); \
    acc[1] += __uint_as_float(v.x & 0xFFFF0000u); \
    acc[2] += __uint_as_float(v.y << 16); \
    acc[3] += __uint_as_float(v.y & 0xFFFF0000u); \
    acc[4] += __uint_as_float(v.z << 16); \
    acc[5] += __uint_as_float(v.z & 0xFFFF0000u); \
    acc[6] += __uint_as_float(v.w << 16); \
    acc[7] += __uint_as_float(v.w & 0xFFFF0000u); \
} while (0)

// ---- MERGED binning + prep; scan via wave-shuffle (2 barriers vs 18) ----
#define PACK_N (N_N * 16)
#define WCAT_N (256 * 512)
#define W1CAT_N (256 * 32)
#define PREP_TOT (PACK_N + WCAT_N + W1CAT_N + N_G)
#define PREP_BLKS ((PREP_TOT + 511) / 512)      // 3407
__global__ __launch_bounds__(512) void k_bfill_prep(const int* __restrict__ ei, int* __restrict__ gcur,
                                                    u32* __restrict__ ebuf,
                                                    const float* __restrict__ x, const float* __restrict__ pos,
                                                    const int* __restrict__ batch,
                                                    const float* __restrict__ W2l, const float* __restrict__ W2r,
                                                    const float* __restrict__ W1l, const float* __restrict__ W1r,
                                                    u16* __restrict__ xpb, float* __restrict__ gcnt,
                                                    u16* __restrict__ wcat, u16* __restrict__ w1cat) {
    __shared__ int hist[NBUK];
    __shared__ int lcur[NBUK];
    __shared__ int gbase[NBUK];
    __shared__ int wsum[8];
    __shared__ u32 stage[CH3];
    __shared__ u16 bstage[CH3];
    int t = threadIdx.x;
    if (blockIdx.x >= NFB) {
        int idx = (blockIdx.x - NFB) * 512 + t;
        if (idx < PACK_N) {
            int n = idx >> 4, f = idx & 15;
            float v = 0.f;
            if (f < 11) v = x[n * 11 + f];
            else if (f < 14) v = pos[n * 3 + (f - 11)];
            xpb[idx] = (u16)f2b(v);
        } else if (idx < PACK_N + WCAT_N) {
            int i2 = idx - PACK_N;
            int n = i2 >> 9, k = i2 & 511;
            float v = (k < 256) ? W2l[k * HID + n] : W2r[(k - 256) * HID + n];
            wcat[(size_t)n * 512 + k] = (u16)f2b(v);
        } else if (idx < PACK_N + WCAT_N + W1CAT_N) {
            int i2 = idx - PACK_N - WCAT_N;
            int n = i2 >> 5, k = i2 & 31;
            float v = 0.f;
            if (k < IND) v = W1l[k * HID + n];
            else if (k >= 16 && k < 16 + IND) v = W1r[(k - 16) * HID + n];
            w1cat[(size_t)n * 32 + k] = (u16)f2b(v);
        } else if (idx < PREP_TOT) {
            int g = idx - PACK_N - WCAT_N - W1CAT_N;
            int lo = 0, hi = N_N;
            while (lo < hi) { int mid = (lo + hi) >> 1; if (batch[mid] < g) lo = mid + 1; else hi = mid; }
            int lo2 = lo, hi2 = N_N;
            while (lo2 < hi2) { int mid = (lo2 + hi2) >> 1; if (batch[mid] < g + 1) lo2 = mid + 1; else hi2 = mid; }
            gcnt[g] = (float)(lo2 - lo);
        }
        return;
    }
    int lane = t & 63, wv = t >> 6;
    int base = blockIdx.x * CH3;
    for (int i = t; i < NBUK; i += 512) hist[i] = 0;
    __syncthreads();
#pragma unroll
    for (int i = 0; i < 16; i++) {
        int e = base + i * 512 + t;
        if (e < N_E) atomicAdd(&hist[ei[N_E + e] >> 8], 1);
    }
    __syncthreads();
    // wave-shuffle inclusive scan of hist over 512 lanes
    int v = (t < NBUK) ? hist[t] : 0;
    int inc = v;
#pragma unroll
    for (int off = 1; off < 64; off <<= 1) {
        int u = __shfl_up(inc, off, 64);
        if (lane >= off) inc += u;
    }
    if (lane == 63) wsum[wv] = inc;
    __syncthreads();
    int pre = 0;
    for (int i = 0; i < wv; i++) pre += wsum[i];
    int inclusive = inc + pre;
    int excl = inclusive - v;                 // exclusive base within stage (reg-saved)
    if (t < NBUK) lcur[t] = excl;
    int blockcnt = 0;
#pragma unroll
    for (int i = 0; i < 8; i++) blockcnt += wsum[i];
    __syncthreads();
#pragma unroll
    for (int i = 0; i < 16; i++) {
        int e = base + i * 512 + t;
        if (e < N_E) {
            int d = ei[N_E + e];
            int s = ei[e];
            int b = d >> 8;
            int p = atomicAdd(&lcur[b], 1);
            stage[p] = (u32)s | ((u32)(d & 255) << 17);
            bstage[p] = (u16)b;
        }
    }
    __syncthreads();
    if (t < NBUK) {
        int c = hist[t];
        int o = c ? atomicAdd(&gcur[t * 16], c) : 0;
        gbase[t] = t * CAP + o - excl;        // so global = gbase[b] + p
    }
    __syncthreads();
#pragma unroll
    for (int i = 0; i < 16; i++) {
        int p = i * 512 + t;
        if (p < blockcnt) {
            int b = bstage[p];
            ebuf[gbase[b] + p] = stage[p];
        }
    }
}

// ---- per-bucket counting sort (static bases; wave-shuffle scan, 4 barriers) ----
__global__ __launch_bounds__(256) void k_sort(const u32* __restrict__ ebuf, const int* __restrict__ gcur,
                                              int* __restrict__ csrc, int* __restrict__ deg,
                                              int* __restrict__ rowp) {
    __shared__ int degL[256];
    __shared__ int curL[256];
    __shared__ int wsum[4];
    int t = threadIdx.x;
    int lane = t & 63, wv = t >> 6;
    int b = blockIdx.x;
    int bs = b * CAP;
    int be = bs + gcur[b * 16];
    degL[t] = 0;
    __syncthreads();
    for (int e = bs + t; e < be; e += 256)
        atomicAdd(&degL[ebuf[e] >> 17], 1);
    __syncthreads();
    int myDeg = degL[t];
    int inc = myDeg;
#pragma unroll
    for (int off = 1; off < 64; off <<= 1) {
        int u = __shfl_up(inc, off, 64);
        if (lane >= off) inc += u;
    }
    if (lane == 63) wsum[wv] = inc;
    __syncthreads();
    int pre = 0;
    for (int i = 0; i < wv; i++) pre += wsum[i];
    int excl = inc + pre - myDeg;
    int node = (b << 8) + t;       // < 100096; deg=0 for node >= N_N
    deg[node] = myDeg;
    rowp[node] = bs + excl;
    curL[t] = bs + excl;
    __syncthreads();
    for (int e = bs + t; e < be; e += 256) {
        u32 w = ebuf[e];
        int p = atomicAdd(&curL[w >> 17], 1);
        csrc[p] = (int)(w & 0x1FFFFu);
    }
}

// ---- layer 1: gather (8 lanes/edge, unroll-2) + MFMA matmul; persists the
// 32-wide z-rows (As) to zb so k_agg can recompute h1 from a 64B gather ----
__global__ __launch_bounds__(256) void k_layer1(const u16* __restrict__ xpb,
                                                const int* __restrict__ rowp, const int* __restrict__ deg,
                                                const int* __restrict__ csrc,
                                                const u16* __restrict__ w1cat, const float* __restrict__ b1,
                                                u16* __restrict__ h1b, u16* __restrict__ zb) {
    __shared__ u16 As[16][32];       // [node][k]: k0..15 = mean(xp) (14,15=0), k16..31 = own row
    __shared__ u16 outS[16][256];    // D staging for coalesced writeout
    int tid = threadIdx.x;
    int wave = tid >> 6, lane = tid & 63;
    int fp = lane & 7;          // feature pair 0..7
    int eg = lane >> 3;         // edge group 0..7
    if (blockIdx.x == 0 && tid < 16)   // zero row at ZROW for k_agg's branchless tails
        *(u32*)(zb + (size_t)ZROW * 32 + tid * 2) = 0;
#pragma unroll
    for (int nn = 0; nn < 4; nn++) {
        int s = wave * 4 + nn;
        int node = blockIdx.x * 16 + s;     // grid covers exactly N_N
        int st = rowp[node], dg = deg[node];
        int end = st + dg;
        float a0 = 0.f, a1 = 0.f, b0 = 0.f, b1v = 0.f;
        int e = st + eg;
        for (; e + 8 < end; e += 16) {      // unroll-2: both csrc loads independent
            int nb1 = csrc[e];
            int nb2 = csrc[e + 8];
            u32 v1 = *(const u32*)(xpb + (size_t)nb1 * 16 + fp * 2);
            u32 v2 = *(const u32*)(xpb + (size_t)nb2 * 16 + fp * 2);
            a0 += __uint_as_float(v1 << 16);
            a1 += __uint_as_float(v1 & 0xFFFF0000u);
            b0 += __uint_as_float(v2 << 16);
            b1v += __uint_as_float(v2 & 0xFFFF0000u);
        }
        if (e < end) {
            int nb = csrc[e];
            u32 v = *(const u32*)(xpb + (size_t)nb * 16 + fp * 2);
            a0 += __uint_as_float(v << 16);
            a1 += __uint_as_float(v & 0xFFFF0000u);
        }
        a0 += b0; a1 += b1v;
        if (eg == 1) {   // own row is already bf16: copy pair directly (k 16..31)
            *(u32*)&As[s][16 + fp * 2] = *(const u32*)(xpb + (size_t)node * 16 + fp * 2);
        }
#pragma unroll
        for (int off = 32; off >= 8; off >>= 1) {
            a0 += __shfl_down(a0, off);
            a1 += __shfl_down(a1, off);
        }
        if (eg == 0) {
            float inv = 1.f / (float)max(dg, 1);
            *(u32*)&As[s][fp * 2] = f2b(a0 * inv) | (f2b(a1 * inv) << 16);
        }
    }
    __syncthreads();
    // persist z-rows: thread t -> node t>>4, u32 pair t&15 (coalesced 1KB/block)
    {
        int s = tid >> 4, kp = tid & 15;
        *(u32*)(zb + (size_t)(blockIdx.x * 16 + s) * 32 + kp * 2) = *(const u32*)&As[s][kp * 2];
    }
    // ---- MFMA phase: wave w covers output feats [w*64, w*64+64) as 4 16x16 tiles ----
    int quad = lane >> 4, m16 = lane & 15;
    bf16x8 afrag = *(const bf16x8*)&As[m16][quad * 8];
#pragma unroll
    for (int u = 0; u < 4; u++) {
        int feat = wave * 64 + u * 16 + m16;
        bf16x8 bfrag = *(const bf16x8*)(w1cat + (size_t)feat * 32 + quad * 8);
        f32x4 d = {0.f, 0.f, 0.f, 0.f};
        d = __builtin_amdgcn_mfma_f32_16x16x32_bf16(afrag, bfrag, d, 0, 0, 0);
        float bj = b1[feat];
#pragma unroll
        for (int i = 0; i < 4; i++) {
            int row = quad * 4 + i;          // node within tile
            outS[row][feat] = (u16)f2b(fmaxf(d[i] + bj, 0.f));
        }
    }
    __syncthreads();
    // ---- coalesced writeout: thread t -> node t>>4, 32B chunk t&15 ----
    int r = tid >> 4, c = tid & 15;
    uint4* dst = (uint4*)(h1b + ((size_t)(blockIdx.x * 16 + r)) * HID + c * 16);
    dst[0] = *(const uint4*)&outS[r][c * 16];
    dst[1] = *(const uint4*)&outS[r][c * 16 + 8];
}

// ---- layer-2 mean aggregation, RECOMPUTE v2 ----
// R1 post-mortem: v1 was latency-bound (Occupancy 10.6% ~= 1 wave/SIMD: unified
// VGPR+AGPR alloc blew past 256 with 16 live f32x4 MFMA temps; 1 chunk of work
// vs ~2000cy dependent prologue per wave). Fixes:
//  * __launch_bounds__(256,3): cap total regs at 170 -> 3 waves/SIMD
//  * NPW=8 nodes per wave: amortize bfrag/bias prologue 8x, contiguous csrc
//  * double-buffered A-frag: next chunk's csrc+zb gather overlaps 16-MFMA cluster
//  * branchless tail via zero-row ZROW + relu algebra:
//      relu(g+b) = max(g,-b)+b; masked rows (z=0) contribute max(0,-b)=relu(-b)
//      => sum_valid relu = acc - nmask*relu(-b) + dg*b   (2 VALU/value in-loop)
__global__ __launch_bounds__(256, 3) void k_agg(const u16* __restrict__ zb, const int* __restrict__ rowp,
                                                const int* __restrict__ deg, const int* __restrict__ csrc,
                                                const u16* __restrict__ w1cat, const float* __restrict__ b1,
                                                u16* __restrict__ mean1b) {
    __shared__ u16 outW[4][256];     // per-wave writeout staging
    int tid = threadIdx.x;
    int wv = tid >> 6, lane = tid & 63;
    int quad = lane >> 4, m16 = lane & 15;
    // hoist B-frags (w1cat, 16KB shared by all waves -> L2 broadcast) + neg-bias
    bf16x8 bfrag[16];
    float nbb[16];
#pragma unroll
    for (int u = 0; u < 16; u++) {
        bfrag[u] = *(const bf16x8*)(w1cat + (size_t)(u * 16 + m16) * 32 + quad * 8);
        nbb[u] = -b1[u * 16 + m16];
    }
    int nbase = (blockIdx.x * 4 + wv) * NPW;     // grid covers exactly N_N
    for (int j = 0; j < NPW; j++) {
        int node = nbase + j;
        int st = rowp[node], dg = deg[node];     // wave-uniform -> s_loads
        int end = st + dg;
        float acc[16] = {};
        int e0 = st + m16;
        int nb = (e0 < end) ? csrc[e0] : ZROW;
        bf16x8 af = *(const bf16x8*)(zb + (size_t)nb * 32 + quad * 8);
        for (int cb = 0; cb < dg; cb += 16) {
            // prefetch next chunk's A-frag (dummy zero-row load past the end)
            int e2 = st + cb + 16 + m16;
            int nb2 = (e2 < end) ? csrc[e2] : ZROW;
            bf16x8 afn = *(const bf16x8*)(zb + (size_t)nb2 * 32 + quad * 8);
#pragma unroll
            for (int u = 0; u < 16; u++) {
                f32x4 d = {0.f, 0.f, 0.f, 0.f};
                d = __builtin_amdgcn_mfma_f32_16x16x32_bf16(af, bfrag[u], d, 0, 0, 0);
                acc[u] += fmaxf(d[0], nbb[u]) + fmaxf(d[1], nbb[u]) +
                          fmaxf(d[2], nbb[u]) + fmaxf(d[3], nbb[u]);
            }
            af = afn;
        }
        int nch = (dg + 15) >> 4;
        float inv = 1.f / (float)max(dg, 1);
        float fdg = (float)dg;
        float fnm = (float)(nch * 16 - dg);
#pragma unroll
        for (int u = 0; u < 16; u++) {
            float a = acc[u];
            a += __shfl_down(a, 32);     // quads {0,1}+{2,3}
            a += __shfl_down(a, 16);     // + quad 1
            float rnb = fmaxf(nbb[u], 0.f);
            a = fmaf(fdg, -nbb[u], a);   // + dg*b
            a = fmaf(-fnm, rnb, a);      // - nmask*relu(-b)
            if (quad == 0) outW[wv][u * 16 + m16] = (u16)f2b(a * inv);
        }
        // same-wave LDS dependency: compiler orders via lgkmcnt; no barrier needed
        if (lane < 32)
            *(uint4*)(mean1b + (size_t)node * HID + (size_t)lane * 8) = *(const uint4*)&outW[wv][lane * 8];
    }
}

// ---- layer 2 (BM=128, Bs double-kt — ~24 us): direct-global A-frags + register
// prefetch; fused relu + Wout-dot + pool atomic ----
__global__ __launch_bounds__(256, 2) void k_layer2(const u16* __restrict__ mean1b, const u16* __restrict__ h1b,
                                                   const u16* __restrict__ wcat, const float* __restrict__ b2,
                                                   const int* __restrict__ batch, const float* __restrict__ Wout,
                                                   float* __restrict__ outsum) {
    __shared__ u16 Bs[2][256][40];
    int tid = threadIdx.x;
    int wave = tid >> 6, lane = tid & 63;
    int quad = lane >> 4, m16 = lane & 15;
    int bm = blockIdx.x;
    const size_t r0 = (size_t)(bm * 128 + wave * 32 + m16) * HID + quad * 8;
    const size_t r1 = r0 + 16 * HID;
    f32x4 acc[2][16] = {};
    uint4 a0 = *(const uint4*)(mean1b + r0);
    uint4 a1 = *(const uint4*)(mean1b + r1);
    for (int kt2 = 0; kt2 < 8; kt2++) {
        __syncthreads();
#pragma unroll
        for (int h = 0; h < 2; h++) {
            int kt = kt2 * 2 + h;
#pragma unroll
            for (int i = 0; i < 4; i++) {
                int cidx = tid + 256 * i;
                int n = cidx >> 2, kc = cidx & 3;
                *(uint4*)&Bs[h][n][kc * 8] =
                    *(const uint4*)(wcat + (size_t)n * 512 + kt * 32 + kc * 8);
            }
        }
        __syncthreads();
#pragma unroll
        for (int h = 0; h < 2; h++) {
            int kt = kt2 * 2 + h;
            uint4 cur0 = a0, cur1 = a1;
            if (kt < 15) {
                int kg = (kt + 1) * 32;
                const u16* An = (kg < 256) ? (mean1b + kg) : (h1b + (kg - 256));
                a0 = *(const uint4*)(An + r0);
                a1 = *(const uint4*)(An + r1);
            }
            bf16x8 af0 = __builtin_bit_cast(bf16x8, cur0);
            bf16x8 af1 = __builtin_bit_cast(bf16x8, cur1);
#pragma unroll
            for (int u = 0; u < 16; u++) {
                bf16x8 bf = *(const bf16x8*)&Bs[h][u * 16 + m16][quad * 8];
                acc[0][u] = __builtin_amdgcn_mfma_f32_16x16x32_bf16(af0, bf, acc[0][u], 0, 0, 0);
                acc[1][u] = __builtin_amdgcn_mfma_f32_16x16x32_bf16(af1, bf, acc[1][u], 0, 0, 0);
            }
        }
    }
    float wo[16], bb[16];
#pragma unroll
    for (int u = 0; u < 16; u++) { int col = u * 16 + m16; wo[u] = Wout[col]; bb[u] = b2[col]; }
#pragma unroll
    for (int t = 0; t < 2; t++) {
#pragma unroll
        for (int i = 0; i < 4; i++) {
            float p = 0.f;
#pragma unroll
            for (int u = 0; u < 16; u++)
                p = fmaf(fmaxf(acc[t][u][i] + bb[u], 0.f), wo[u], p);
#pragma unroll
            for (int off = 8; off > 0; off >>= 1) p += __shfl_down(p, off, 16);
            int row = bm * 128 + wave * 32 + t * 16 + quad * 4 + i;
            if (m16 == 0 && row < N_N) atomicAdd(&outsum[batch[row]], p);
        }
    }
}

// ---- output head ----
__global__ __launch_bounds__(256) void k_out(const float* __restrict__ outsum, const float* __restrict__ gcnt,
                                             const float* __restrict__ bout, float* __restrict__ out) {
    int g = blockIdx.x * 256 + threadIdx.x;
    if (g < N_G) out[g] = outsum[g] / fmaxf(gcnt[g], 1.f) + bout[0];
}

extern "C" void kernel_launch(void* const* d_in, const int* in_sizes, int n_in,
                              void* d_out, int out_size, void* d_ws, size_t ws_size,
                              hipStream_t stream) {
    const float* x    = (const float*)d_in[0];
    const float* pos  = (const float*)d_in[1];
    const int*   ei   = (const int*)d_in[2];
    const int*   batch= (const int*)d_in[3];
    const float* W1l  = (const float*)d_in[4];
    const float* b1   = (const float*)d_in[5];
    const float* W1r  = (const float*)d_in[6];
    const float* W2l  = (const float*)d_in[7];
    const float* b2   = (const float*)d_in[8];
    const float* W2r  = (const float*)d_in[9];
    const float* Wout = (const float*)d_in[10];
    const float* bout = (const float*)d_in[11];
    float* out = (float*)d_out;
    float* ws  = (float*)d_ws;

    float* outs  = ws + OFF_OUTS;
    int*   gcur  = (int*)(ws + OFF_GCUR);
    float* gcnt  = ws + OFF_GCNT;
    int*   rowp  = (int*)(ws + OFF_ROWP);
    int*   deg   = (int*)(ws + OFF_DEG);
    u32*   ebuf  = (u32*)(ws + OFF_EBUF);
    int*   csrc  = (int*)(ws + OFF_CSRC);
    u16*   h1b   = (u16*)(ws + OFF_H1B);
    u16*   wcat  = (u16*)(ws + OFF_WCAT);
    u16*   xpb   = (u16*)(ws + OFF_XP);
    u16*   mean1b= (u16*)(ws + OFF_MEAN1B);
    u16*   w1cat = (u16*)(ws + OFF_W1CAT);
    u16*   zb    = (u16*)ebuf;      // ebuf is dead after k_sort; reuse for z-rows

    hipMemsetAsync(d_ws, 0, ZERO_BYTES, stream);
    k_bfill_prep<<<NFB + PREP_BLKS, 512, 0, stream>>>(
        ei, gcur, ebuf, x, pos, batch, W2l, W2r, W1l, W1r, xpb, gcnt, wcat, w1cat);
    k_sort  <<<NBUK, 256, 0, stream>>>(ebuf, gcur, csrc, deg, rowp);
    k_layer1<<<N_N / 16, 256, 0, stream>>>(xpb, rowp, deg, csrc, w1cat, b1, h1b, zb);
    k_agg   <<<N_N / (4 * NPW), 256, 0, stream>>>(zb, rowp, deg, csrc, w1cat, b1, mean1b);
    k_layer2<<<(N_N + 127) / 128, 256, 0, stream>>>(mean1b, h1b, wcat, b2, batch, Wout, outs);
    k_out   <<<(N_G + 255) / 256, 256, 0, stream>>>(outs, gcnt, bout, out);
}

// Round 3
// 558.739 us; speedup vs baseline: 1.1807x; 1.0498x over previous
//
#include <hip/hip_runtime.h>

#define N_N 100000
#define N_E 1600000
#define N_G 5000
#define HID 256
#define IND 14

#define NBUK 391      // buckets: dst>>8, 256 nodes each (391*256 = 100096)
#define CAP 5120      // static per-bucket capacity (E[cnt]=4096, sigma~64; +16 sigma)
#define CH3 8192      // edges per binning block (512 threads)
#define NFB 196       // ceil(N_E/CH3)

typedef __bf16 bf16x8 __attribute__((ext_vector_type(8)));
typedef float f32x4 __attribute__((ext_vector_type(4)));
typedef unsigned short u16;
typedef unsigned int u32;

// ---- workspace layout (units of 4 bytes) ----
constexpr size_t OFF_OUTS  = 0;          // float[5120]   (zeroed)
constexpr size_t OFF_GCUR  = 5120;       // int[391*16]   (zeroed, 64B-padded cursors)
constexpr size_t ZERO_END  = 11520;
constexpr size_t ZERO_BYTES = ZERO_END * 4;
constexpr size_t OFF_GCNT  = 11520;      // float[5120] (fully written)
constexpr size_t OFF_ROWP  = 16640;      // int[100096]
constexpr size_t OFF_DEG   = 116736;     // int[100096]
constexpr size_t OFF_EBUF  = 216832;     // u32[391*5120]; dead after k_sort -> reused as zb (bf16[(100000+1)*32] = 6.4MB < 8MB)
constexpr size_t OFF_CSRC  = 2218752;    // int[391*5120]
constexpr size_t OFF_H1B   = 4220672;    // bf16[100096*256] -> ends 17032960
constexpr size_t OFF_WCAT  = 17032960;   // bf16[256*512]    -> ends 17098496
constexpr size_t OFF_XP    = 17098496;   // bf16[N*16]       -> ends 17898496
constexpr size_t OFF_MEAN1B= 17898496;   // bf16[100096*256] -> ends 30710784
constexpr size_t OFF_W1CAT = 30710784;   // bf16[256*32]     -> ends 30714880
// end = 30714880 floats ~= 123 MB

#define ZROW N_N      // all-zero z-row for branchless chunk tails
#define NPW 8         // nodes per wave in k_agg

__device__ __forceinline__ u32 f2b(float f) {
    u32 u = __float_as_uint(f);
    u32 r = u + 0x7FFFu + ((u >> 16) & 1u);
    return r >> 16;
}

#define ADD8(acc, v) do { \
    acc[0] += __uint_as_float(v.x << 16); \
    acc[1] += __uint_as_float(v.x & 0xFFFF0000u); \
    acc[2] += __uint_as_float(v.y << 16); \
    acc[3] += __uint_as_float(v.y & 0xFFFF0000u); \
    acc[4] += __uint_as_float(v.z << 16); \
    acc[5] += __uint_as_float(v.z & 0xFFFF0000u); \
    acc[6] += __uint_as_float(v.w << 16); \
    acc[7] += __uint_as_float(v.w & 0xFFFF0000u); \
} while (0)

// ---- MERGED binning + prep; scan via wave-shuffle (2 barriers vs 18) ----
#define PACK_N (N_N * 16)
#define WCAT_N (256 * 512)
#define W1CAT_N (256 * 32)
#define PREP_TOT (PACK_N + WCAT_N + W1CAT_N + N_G)
#define PREP_BLKS ((PREP_TOT + 511) / 512)      // 3407
__global__ __launch_bounds__(512) void k_bfill_prep(const int* __restrict__ ei, int* __restrict__ gcur,
                                                    u32* __restrict__ ebuf,
                                                    const float* __restrict__ x, const float* __restrict__ pos,
                                                    const int* __restrict__ batch,
                                                    const float* __restrict__ W2l, const float* __restrict__ W2r,
                                                    const float* __restrict__ W1l, const float* __restrict__ W1r,
                                                    u16* __restrict__ xpb, float* __restrict__ gcnt,
                                                    u16* __restrict__ wcat, u16* __restrict__ w1cat) {
    __shared__ int hist[NBUK];
    __shared__ int lcur[NBUK];
    __shared__ int gbase[NBUK];
    __shared__ int wsum[8];
    __shared__ u32 stage[CH3];
    __shared__ u16 bstage[CH3];
    int t = threadIdx.x;
    if (blockIdx.x >= NFB) {
        int idx = (blockIdx.x - NFB) * 512 + t;
        if (idx < PACK_N) {
            int n = idx >> 4, f = idx & 15;
            float v = 0.f;
            if (f < 11) v = x[n * 11 + f];
            else if (f < 14) v = pos[n * 3 + (f - 11)];
            xpb[idx] = (u16)f2b(v);
        } else if (idx < PACK_N + WCAT_N) {
            int i2 = idx - PACK_N;
            int n = i2 >> 9, k = i2 & 511;
            float v = (k < 256) ? W2l[k * HID + n] : W2r[(k - 256) * HID + n];
            wcat[(size_t)n * 512 + k] = (u16)f2b(v);
        } else if (idx < PACK_N + WCAT_N + W1CAT_N) {
            int i2 = idx - PACK_N - WCAT_N;
            int n = i2 >> 5, k = i2 & 31;
            float v = 0.f;
            if (k < IND) v = W1l[k * HID + n];
            else if (k >= 16 && k < 16 + IND) v = W1r[(k - 16) * HID + n];
            w1cat[(size_t)n * 32 + k] = (u16)f2b(v);
        } else if (idx < PREP_TOT) {
            int g = idx - PACK_N - WCAT_N - W1CAT_N;
            int lo = 0, hi = N_N;
            while (lo < hi) { int mid = (lo + hi) >> 1; if (batch[mid] < g) lo = mid + 1; else hi = mid; }
            int lo2 = lo, hi2 = N_N;
            while (lo2 < hi2) { int mid = (lo2 + hi2) >> 1; if (batch[mid] < g + 1) lo2 = mid + 1; else hi2 = mid; }
            gcnt[g] = (float)(lo2 - lo);
        }
        return;
    }
    int lane = t & 63, wv = t >> 6;
    int base = blockIdx.x * CH3;
    for (int i = t; i < NBUK; i += 512) hist[i] = 0;
    __syncthreads();
#pragma unroll
    for (int i = 0; i < 16; i++) {
        int e = base + i * 512 + t;
        if (e < N_E) atomicAdd(&hist[ei[N_E + e] >> 8], 1);
    }
    __syncthreads();
    // wave-shuffle inclusive scan of hist over 512 lanes
    int v = (t < NBUK) ? hist[t] : 0;
    int inc = v;
#pragma unroll
    for (int off = 1; off < 64; off <<= 1) {
        int u = __shfl_up(inc, off, 64);
        if (lane >= off) inc += u;
    }
    if (lane == 63) wsum[wv] = inc;
    __syncthreads();
    int pre = 0;
    for (int i = 0; i < wv; i++) pre += wsum[i];
    int inclusive = inc + pre;
    int excl = inclusive - v;                 // exclusive base within stage (reg-saved)
    if (t < NBUK) lcur[t] = excl;
    int blockcnt = 0;
#pragma unroll
    for (int i = 0; i < 8; i++) blockcnt += wsum[i];
    __syncthreads();
#pragma unroll
    for (int i = 0; i < 16; i++) {
        int e = base + i * 512 + t;
        if (e < N_E) {
            int d = ei[N_E + e];
            int s = ei[e];
            int b = d >> 8;
            int p = atomicAdd(&lcur[b], 1);
            stage[p] = (u32)s | ((u32)(d & 255) << 17);
            bstage[p] = (u16)b;
        }
    }
    __syncthreads();
    if (t < NBUK) {
        int c = hist[t];
        int o = c ? atomicAdd(&gcur[t * 16], c) : 0;
        gbase[t] = t * CAP + o - excl;        // so global = gbase[b] + p
    }
    __syncthreads();
#pragma unroll
    for (int i = 0; i < 16; i++) {
        int p = i * 512 + t;
        if (p < blockcnt) {
            int b = bstage[p];
            ebuf[gbase[b] + p] = stage[p];
        }
    }
}

// ---- per-bucket counting sort (static bases; wave-shuffle scan, 4 barriers) ----
__global__ __launch_bounds__(256) void k_sort(const u32* __restrict__ ebuf, const int* __restrict__ gcur,
                                              int* __restrict__ csrc, int* __restrict__ deg,
                                              int* __restrict__ rowp) {
    __shared__ int degL[256];
    __shared__ int curL[256];
    __shared__ int wsum[4];
    int t = threadIdx.x;
    int lane = t & 63, wv = t >> 6;
    int b = blockIdx.x;
    int bs = b * CAP;
    int be = bs + gcur[b * 16];
    degL[t] = 0;
    __syncthreads();
    for (int e = bs + t; e < be; e += 256)
        atomicAdd(&degL[ebuf[e] >> 17], 1);
    __syncthreads();
    int myDeg = degL[t];
    int inc = myDeg;
#pragma unroll
    for (int off = 1; off < 64; off <<= 1) {
        int u = __shfl_up(inc, off, 64);
        if (lane >= off) inc += u;
    }
    if (lane == 63) wsum[wv] = inc;
    __syncthreads();
    int pre = 0;
    for (int i = 0; i < wv; i++) pre += wsum[i];
    int excl = inc + pre - myDeg;
    int node = (b << 8) + t;       // < 100096; deg=0 for node >= N_N
    deg[node] = myDeg;
    rowp[node] = bs + excl;
    curL[t] = bs + excl;
    __syncthreads();
    for (int e = bs + t; e < be; e += 256) {
        u32 w = ebuf[e];
        int p = atomicAdd(&curL[w >> 17], 1);
        csrc[p] = (int)(w & 0x1FFFFu);
    }
}

// ---- layer 1: gather (8 lanes/edge, unroll-2) + MFMA matmul; persists the
// 32-wide z-rows (As) to zb so k_agg can recompute h1 from a 64B gather ----
__global__ __launch_bounds__(256) void k_layer1(const u16* __restrict__ xpb,
                                                const int* __restrict__ rowp, const int* __restrict__ deg,
                                                const int* __restrict__ csrc,
                                                const u16* __restrict__ w1cat, const float* __restrict__ b1,
                                                u16* __restrict__ h1b, u16* __restrict__ zb) {
    __shared__ u16 As[16][32];       // [node][k]: k0..15 = mean(xp) (14,15=0), k16..31 = own row
    __shared__ u16 outS[16][256];    // D staging for coalesced writeout
    int tid = threadIdx.x;
    int wave = tid >> 6, lane = tid & 63;
    int fp = lane & 7;          // feature pair 0..7
    int eg = lane >> 3;         // edge group 0..7
    if (blockIdx.x == 0 && tid < 16)   // zero row at ZROW for k_agg's branchless tails
        *(u32*)(zb + (size_t)ZROW * 32 + tid * 2) = 0;
#pragma unroll
    for (int nn = 0; nn < 4; nn++) {
        int s = wave * 4 + nn;
        int node = blockIdx.x * 16 + s;     // grid covers exactly N_N
        int st = rowp[node], dg = deg[node];
        int end = st + dg;
        float a0 = 0.f, a1 = 0.f, b0 = 0.f, b1v = 0.f;
        int e = st + eg;
        for (; e + 8 < end; e += 16) {      // unroll-2: both csrc loads independent
            int nb1 = csrc[e];
            int nb2 = csrc[e + 8];
            u32 v1 = *(const u32*)(xpb + (size_t)nb1 * 16 + fp * 2);
            u32 v2 = *(const u32*)(xpb + (size_t)nb2 * 16 + fp * 2);
            a0 += __uint_as_float(v1 << 16);
            a1 += __uint_as_float(v1 & 0xFFFF0000u);
            b0 += __uint_as_float(v2 << 16);
            b1v += __uint_as_float(v2 & 0xFFFF0000u);
        }
        if (e < end) {
            int nb = csrc[e];
            u32 v = *(const u32*)(xpb + (size_t)nb * 16 + fp * 2);
            a0 += __uint_as_float(v << 16);
            a1 += __uint_as_float(v & 0xFFFF0000u);
        }
        a0 += b0; a1 += b1v;
        if (eg == 1) {   // own row is already bf16: copy pair directly (k 16..31)
            *(u32*)&As[s][16 + fp * 2] = *(const u32*)(xpb + (size_t)node * 16 + fp * 2);
        }
#pragma unroll
        for (int off = 32; off >= 8; off >>= 1) {
            a0 += __shfl_down(a0, off);
            a1 += __shfl_down(a1, off);
        }
        if (eg == 0) {
            float inv = 1.f / (float)max(dg, 1);
            *(u32*)&As[s][fp * 2] = f2b(a0 * inv) | (f2b(a1 * inv) << 16);
        }
    }
    __syncthreads();
    // persist z-rows: thread t -> node t>>4, u32 pair t&15 (coalesced 1KB/block)
    {
        int s = tid >> 4, kp = tid & 15;
        *(u32*)(zb + (size_t)(blockIdx.x * 16 + s) * 32 + kp * 2) = *(const u32*)&As[s][kp * 2];
    }
    // ---- MFMA phase: wave w covers output feats [w*64, w*64+64) as 4 16x16 tiles ----
    int quad = lane >> 4, m16 = lane & 15;
    bf16x8 afrag = *(const bf16x8*)&As[m16][quad * 8];
#pragma unroll
    for (int u = 0; u < 4; u++) {
        int feat = wave * 64 + u * 16 + m16;
        bf16x8 bfrag = *(const bf16x8*)(w1cat + (size_t)feat * 32 + quad * 8);
        f32x4 d = {0.f, 0.f, 0.f, 0.f};
        d = __builtin_amdgcn_mfma_f32_16x16x32_bf16(afrag, bfrag, d, 0, 0, 0);
        float bj = b1[feat];
#pragma unroll
        for (int i = 0; i < 4; i++) {
            int row = quad * 4 + i;          // node within tile
            outS[row][feat] = (u16)f2b(fmaxf(d[i] + bj, 0.f));
        }
    }
    __syncthreads();
    // ---- coalesced writeout: thread t -> node t>>4, 32B chunk t&15 ----
    int r = tid >> 4, c = tid & 15;
    uint4* dst = (uint4*)(h1b + ((size_t)(blockIdx.x * 16 + r)) * HID + c * 16);
    dst[0] = *(const uint4*)&outS[r][c * 16];
    dst[1] = *(const uint4*)&outS[r][c * 16 + 8];
}

// ---- layer-2 mean aggregation, RECOMPUTE v3 ----
// R2 post-mortem: the (256,3) reg cap made the compiler SPILL bfrag/acc
// (WRITE_SIZE 50->225MB, FETCH 65->266MB = scratch round-trips in the inner
// loop at ~200-900cy each). Fix: w1cat B-frags live in LDS (16KB, shared by
// all 4 waves, loaded once per block) -> reg budget ~60, no spills, and
// __launch_bounds__(256,4) holds 4 waves/SIMD for latency hiding.
// Branchless ZROW tail + relu algebra (correctness proven in R2):
//   relu(g+b) = max(g,-b)+b; masked rows (z=0) contribute relu(-b)
//   => sum_valid relu = acc - nmask*relu(-b) + dg*b
__global__ __launch_bounds__(256, 4) void k_agg(const u16* __restrict__ zb, const int* __restrict__ rowp,
                                                const int* __restrict__ deg, const int* __restrict__ csrc,
                                                const u16* __restrict__ w1cat, const float* __restrict__ b1,
                                                u16* __restrict__ mean1b) {
    __shared__ u16 Bs[256 * 32];     // full w1cat copy: 16 KB
    __shared__ u16 outW[4][256];     // per-wave writeout staging
    int tid = threadIdx.x;
    int wv = tid >> 6, lane = tid & 63;
    int quad = lane >> 4, m16 = lane & 15;
    {   // cooperative 16KB copy: 64B per thread, coalesced
        const uint4* src = (const uint4*)w1cat;
        uint4* dst = (uint4*)Bs;
#pragma unroll
        for (int i = 0; i < 4; i++) dst[tid + 256 * i] = src[tid + 256 * i];
    }
    float nbb[16];
#pragma unroll
    for (int u = 0; u < 16; u++) nbb[u] = -b1[u * 16 + m16];
    __syncthreads();
    int nbase = (blockIdx.x * 4 + wv) * NPW;     // grid covers exactly N_N
    for (int j = 0; j < NPW; j++) {
        int node = nbase + j;
        int st = rowp[node], dg = deg[node];     // wave-uniform
        int end = st + dg;
        float acc[16] = {};
        int e0 = st + m16;
        int nb = (e0 < end) ? csrc[e0] : ZROW;
        bf16x8 af = *(const bf16x8*)(zb + (size_t)nb * 32 + quad * 8);
        for (int cb = 0; cb < dg; cb += 16) {
            // prefetch next chunk's A-frag (dummy zero-row load past the end)
            int e2 = st + cb + 16 + m16;
            int nb2 = (e2 < end) ? csrc[e2] : ZROW;
            bf16x8 afn = *(const bf16x8*)(zb + (size_t)nb2 * 32 + quad * 8);
#pragma unroll
            for (int u = 0; u < 16; u++) {
                bf16x8 bf = *(const bf16x8*)&Bs[(u * 16 + m16) * 32 + quad * 8];
                f32x4 d = {0.f, 0.f, 0.f, 0.f};
                d = __builtin_amdgcn_mfma_f32_16x16x32_bf16(af, bf, d, 0, 0, 0);
                acc[u] += (fmaxf(d[0], nbb[u]) + fmaxf(d[1], nbb[u])) +
                          (fmaxf(d[2], nbb[u]) + fmaxf(d[3], nbb[u]));
            }
            af = afn;
        }
        int nch = (dg + 15) >> 4;
        float inv = 1.f / (float)max(dg, 1);
        float fdg = (float)dg;
        float fnm = (float)(nch * 16 - dg);
#pragma unroll
        for (int u = 0; u < 16; u++) {
            float a = acc[u];
            a += __shfl_down(a, 32);     // quads {0,1}+{2,3}
            a += __shfl_down(a, 16);     // + quad 1
            float rnb = fmaxf(nbb[u], 0.f);
            a = fmaf(fdg, -nbb[u], a);   // + dg*b
            a = fmaf(-fnm, rnb, a);      // - nmask*relu(-b)
            if (quad == 0) outW[wv][u * 16 + m16] = (u16)f2b(a * inv);
        }
        // same-wave LDS dependency: compiler orders via lgkmcnt; no barrier needed
        if (lane < 32)
            *(uint4*)(mean1b + (size_t)node * HID + (size_t)lane * 8) = *(const uint4*)&outW[wv][lane * 8];
    }
}

// ---- layer 2 (BM=128, Bs double-kt — ~24 us): direct-global A-frags + register
// prefetch; fused relu + Wout-dot + pool atomic ----
__global__ __launch_bounds__(256, 2) void k_layer2(const u16* __restrict__ mean1b, const u16* __restrict__ h1b,
                                                   const u16* __restrict__ wcat, const float* __restrict__ b2,
                                                   const int* __restrict__ batch, const float* __restrict__ Wout,
                                                   float* __restrict__ outsum) {
    __shared__ u16 Bs[2][256][40];
    int tid = threadIdx.x;
    int wave = tid >> 6, lane = tid & 63;
    int quad = lane >> 4, m16 = lane & 15;
    int bm = blockIdx.x;
    const size_t r0 = (size_t)(bm * 128 + wave * 32 + m16) * HID + quad * 8;
    const size_t r1 = r0 + 16 * HID;
    f32x4 acc[2][16] = {};
    uint4 a0 = *(const uint4*)(mean1b + r0);
    uint4 a1 = *(const uint4*)(mean1b + r1);
    for (int kt2 = 0; kt2 < 8; kt2++) {
        __syncthreads();
#pragma unroll
        for (int h = 0; h < 2; h++) {
            int kt = kt2 * 2 + h;
#pragma unroll
            for (int i = 0; i < 4; i++) {
                int cidx = tid + 256 * i;
                int n = cidx >> 2, kc = cidx & 3;
                *(uint4*)&Bs[h][n][kc * 8] =
                    *(const uint4*)(wcat + (size_t)n * 512 + kt * 32 + kc * 8);
            }
        }
        __syncthreads();
#pragma unroll
        for (int h = 0; h < 2; h++) {
            int kt = kt2 * 2 + h;
            uint4 cur0 = a0, cur1 = a1;
            if (kt < 15) {
                int kg = (kt + 1) * 32;
                const u16* An = (kg < 256) ? (mean1b + kg) : (h1b + (kg - 256));
                a0 = *(const uint4*)(An + r0);
                a1 = *(const uint4*)(An + r1);
            }
            bf16x8 af0 = __builtin_bit_cast(bf16x8, cur0);
            bf16x8 af1 = __builtin_bit_cast(bf16x8, cur1);
#pragma unroll
            for (int u = 0; u < 16; u++) {
                bf16x8 bf = *(const bf16x8*)&Bs[h][u * 16 + m16][quad * 8];
                acc[0][u] = __builtin_amdgcn_mfma_f32_16x16x32_bf16(af0, bf, acc[0][u], 0, 0, 0);
                acc[1][u] = __builtin_amdgcn_mfma_f32_16x16x32_bf16(af1, bf, acc[1][u], 0, 0, 0);
            }
        }
    }
    float wo[16], bb[16];
#pragma unroll
    for (int u = 0; u < 16; u++) { int col = u * 16 + m16; wo[u] = Wout[col]; bb[u] = b2[col]; }
#pragma unroll
    for (int t = 0; t < 2; t++) {
#pragma unroll
        for (int i = 0; i < 4; i++) {
            float p = 0.f;
#pragma unroll
            for (int u = 0; u < 16; u++)
                p = fmaf(fmaxf(acc[t][u][i] + bb[u], 0.f), wo[u], p);
#pragma unroll
            for (int off = 8; off > 0; off >>= 1) p += __shfl_down(p, off, 16);
            int row = bm * 128 + wave * 32 + t * 16 + quad * 4 + i;
            if (m16 == 0 && row < N_N) atomicAdd(&outsum[batch[row]], p);
        }
    }
}

// ---- output head ----
__global__ __launch_bounds__(256) void k_out(const float* __restrict__ outsum, const float* __restrict__ gcnt,
                                             const float* __restrict__ bout, float* __restrict__ out) {
    int g = blockIdx.x * 256 + threadIdx.x;
    if (g < N_G) out[g] = outsum[g] / fmaxf(gcnt[g], 1.f) + bout[0];
}

extern "C" void kernel_launch(void* const* d_in, const int* in_sizes, int n_in,
                              void* d_out, int out_size, void* d_ws, size_t ws_size,
                              hipStream_t stream) {
    const float* x    = (const float*)d_in[0];
    const float* pos  = (const float*)d_in[1];
    const int*   ei   = (const int*)d_in[2];
    const int*   batch= (const int*)d_in[3];
    const float* W1l  = (const float*)d_in[4];
    const float* b1   = (const float*)d_in[5];
    const float* W1r  = (const float*)d_in[6];
    const float* W2l  = (const float*)d_in[7];
    const float* b2   = (const float*)d_in[8];
    const float* W2r  = (const float*)d_in[9];
    const float* Wout = (const float*)d_in[10];
    const float* bout = (const float*)d_in[11];
    float* out = (float*)d_out;
    float* ws  = (float*)d_ws;

    float* outs  = ws + OFF_OUTS;
    int*   gcur  = (int*)(ws + OFF_GCUR);
    float* gcnt  = ws + OFF_GCNT;
    int*   rowp  = (int*)(ws + OFF_ROWP);
    int*   deg   = (int*)(ws + OFF_DEG);
    u32*   ebuf  = (u32*)(ws + OFF_EBUF);
    int*   csrc  = (int*)(ws + OFF_CSRC);
    u16*   h1b   = (u16*)(ws + OFF_H1B);
    u16*   wcat  = (u16*)(ws + OFF_WCAT);
    u16*   xpb   = (u16*)(ws + OFF_XP);
    u16*   mean1b= (u16*)(ws + OFF_MEAN1B);
    u16*   w1cat = (u16*)(ws + OFF_W1CAT);
    u16*   zb    = (u16*)ebuf;      // ebuf is dead after k_sort; reuse for z-rows

    hipMemsetAsync(d_ws, 0, ZERO_BYTES, stream);
    k_bfill_prep<<<NFB + PREP_BLKS, 512, 0, stream>>>(
        ei, gcur, ebuf, x, pos, batch, W2l, W2r, W1l, W1r, xpb, gcnt, wcat, w1cat);
    k_sort  <<<NBUK, 256, 0, stream>>>(ebuf, gcur, csrc, deg, rowp);
    k_layer1<<<N_N / 16, 256, 0, stream>>>(xpb, rowp, deg, csrc, w1cat, b1, h1b, zb);
    k_agg   <<<N_N / (4 * NPW), 256, 0, stream>>>(zb, rowp, deg, csrc, w1cat, b1, mean1b);
    k_layer2<<<(N_N + 127) / 128, 256, 0, stream>>>(mean1b, h1b, wcat, b2, batch, Wout, outs);
    k_out   <<<(N_G + 255) / 256, 256, 0, stream>>>(outs, gcnt, bout, out);
}

// Round 5
// 347.359 us; speedup vs baseline: 1.8992x; 1.6085x over previous
//
#include <hip/hip_runtime.h>

#define N_N 100000
#define N_E 1600000
#define N_G 5000
#define HID 256
#define IND 14

#define NBUK 391      // buckets: dst>>8, 256 nodes each (391*256 = 100096)
#define CAP 5120      // static per-bucket capacity (E[cnt]=4096, sigma~64; +16 sigma)
#define CH3 8192      // edges per binning block (512 threads)
#define NFB 196       // ceil(N_E/CH3)

typedef __bf16 bf16x8 __attribute__((ext_vector_type(8)));
typedef float f32x4 __attribute__((ext_vector_type(4)));
typedef unsigned short u16;
typedef unsigned int u32;

// ---- workspace layout (units of 4 bytes) ----
constexpr size_t OFF_OUTS  = 0;          // float[5120]   (zeroed)
constexpr size_t OFF_GCUR  = 5120;       // int[391*16]   (zeroed, 64B-padded cursors)
constexpr size_t ZERO_END  = 11520;
constexpr size_t ZERO_BYTES = ZERO_END * 4;
constexpr size_t OFF_GCNT  = 11520;      // float[5120] (fully written)
constexpr size_t OFF_ROWP  = 16640;      // int[100096]
constexpr size_t OFF_DEG   = 116736;     // int[100096]
constexpr size_t OFF_EBUF  = 216832;     // u32[391*5120]; dead after k_sort -> reused as zb (bf16[(100000+1)*32] = 6.4MB < 8MB)
constexpr size_t OFF_CSRC  = 2218752;    // int[391*5120]
constexpr size_t OFF_H1B   = 4220672;    // bf16[100096*256] -> ends 17032960
constexpr size_t OFF_WCAT  = 17032960;   // bf16[256*512]    -> ends 17098496
constexpr size_t OFF_XP    = 17098496;   // bf16[N*16]       -> ends 17898496
constexpr size_t OFF_MEAN1B= 17898496;   // bf16[100096*256] -> ends 30710784
constexpr size_t OFF_W1CAT = 30710784;   // bf16[256*32]     -> ends 30714880
// end = 30714880 floats ~= 123 MB

#define ZROW N_N      // all-zero z-row for branchless chunk tails
#define NPW 8         // nodes per wave-pair in k_agg

__device__ __forceinline__ u32 f2b(float f) {
    u32 u = __float_as_uint(f);
    u32 r = u + 0x7FFFu + ((u >> 16) & 1u);
    return r >> 16;
}

#define ADD8(acc, v) do { \
    acc[0] += __uint_as_float(v.x << 16); \
    acc[1] += __uint_as_float(v.x & 0xFFFF0000u); \
    acc[2] += __uint_as_float(v.y << 16); \
    acc[3] += __uint_as_float(v.y & 0xFFFF0000u); \
    acc[4] += __uint_as_float(v.z << 16); \
    acc[5] += __uint_as_float(v.z & 0xFFFF0000u); \
    acc[6] += __uint_as_float(v.w << 16); \
    acc[7] += __uint_as_float(v.w & 0xFFFF0000u); \
} while (0)

// ---- MERGED binning + prep; scan via wave-shuffle (2 barriers vs 18) ----
#define PACK_N (N_N * 16)
#define WCAT_N (256 * 512)
#define W1CAT_N (256 * 32)
#define PREP_TOT (PACK_N + WCAT_N + W1CAT_N + N_G)
#define PREP_BLKS ((PREP_TOT + 511) / 512)      // 3407
__global__ __launch_bounds__(512) void k_bfill_prep(const int* __restrict__ ei, int* __restrict__ gcur,
                                                    u32* __restrict__ ebuf,
                                                    const float* __restrict__ x, const float* __restrict__ pos,
                                                    const int* __restrict__ batch,
                                                    const float* __restrict__ W2l, const float* __restrict__ W2r,
                                                    const float* __restrict__ W1l, const float* __restrict__ W1r,
                                                    u16* __restrict__ xpb, float* __restrict__ gcnt,
                                                    u16* __restrict__ wcat, u16* __restrict__ w1cat) {
    __shared__ int hist[NBUK];
    __shared__ int lcur[NBUK];
    __shared__ int gbase[NBUK];
    __shared__ int wsum[8];
    __shared__ u32 stage[CH3];
    __shared__ u16 bstage[CH3];
    int t = threadIdx.x;
    if (blockIdx.x >= NFB) {
        int idx = (blockIdx.x - NFB) * 512 + t;
        if (idx < PACK_N) {
            int n = idx >> 4, f = idx & 15;
            float v = 0.f;
            if (f < 11) v = x[n * 11 + f];
            else if (f < 14) v = pos[n * 3 + (f - 11)];
            xpb[idx] = (u16)f2b(v);
        } else if (idx < PACK_N + WCAT_N) {
            int i2 = idx - PACK_N;
            int n = i2 >> 9, k = i2 & 511;
            float v = (k < 256) ? W2l[k * HID + n] : W2r[(k - 256) * HID + n];
            wcat[(size_t)n * 512 + k] = (u16)f2b(v);
        } else if (idx < PACK_N + WCAT_N + W1CAT_N) {
            int i2 = idx - PACK_N - WCAT_N;
            int n = i2 >> 5, k = i2 & 31;
            float v = 0.f;
            if (k < IND) v = W1l[k * HID + n];
            else if (k >= 16 && k < 16 + IND) v = W1r[(k - 16) * HID + n];
            w1cat[(size_t)n * 32 + k] = (u16)f2b(v);
        } else if (idx < PREP_TOT) {
            int g = idx - PACK_N - WCAT_N - W1CAT_N;
            int lo = 0, hi = N_N;
            while (lo < hi) { int mid = (lo + hi) >> 1; if (batch[mid] < g) lo = mid + 1; else hi = mid; }
            int lo2 = lo, hi2 = N_N;
            while (lo2 < hi2) { int mid = (lo2 + hi2) >> 1; if (batch[mid] < g + 1) lo2 = mid + 1; else hi2 = mid; }
            gcnt[g] = (float)(lo2 - lo);
        }
        return;
    }
    int lane = t & 63, wv = t >> 6;
    int base = blockIdx.x * CH3;
    for (int i = t; i < NBUK; i += 512) hist[i] = 0;
    __syncthreads();
#pragma unroll
    for (int i = 0; i < 16; i++) {
        int e = base + i * 512 + t;
        if (e < N_E) atomicAdd(&hist[ei[N_E + e] >> 8], 1);
    }
    __syncthreads();
    // wave-shuffle inclusive scan of hist over 512 lanes
    int v = (t < NBUK) ? hist[t] : 0;
    int inc = v;
#pragma unroll
    for (int off = 1; off < 64; off <<= 1) {
        int u = __shfl_up(inc, off, 64);
        if (lane >= off) inc += u;
    }
    if (lane == 63) wsum[wv] = inc;
    __syncthreads();
    int pre = 0;
    for (int i = 0; i < wv; i++) pre += wsum[i];
    int inclusive = inc + pre;
    int excl = inclusive - v;                 // exclusive base within stage (reg-saved)
    if (t < NBUK) lcur[t] = excl;
    int blockcnt = 0;
#pragma unroll
    for (int i = 0; i < 8; i++) blockcnt += wsum[i];
    __syncthreads();
#pragma unroll
    for (int i = 0; i < 16; i++) {
        int e = base + i * 512 + t;
        if (e < N_E) {
            int d = ei[N_E + e];
            int s = ei[e];
            int b = d >> 8;
            int p = atomicAdd(&lcur[b], 1);
            stage[p] = (u32)s | ((u32)(d & 255) << 17);
            bstage[p] = (u16)b;
        }
    }
    __syncthreads();
    if (t < NBUK) {
        int c = hist[t];
        int o = c ? atomicAdd(&gcur[t * 16], c) : 0;
        gbase[t] = t * CAP + o - excl;        // so global = gbase[b] + p
    }
    __syncthreads();
#pragma unroll
    for (int i = 0; i < 16; i++) {
        int p = i * 512 + t;
        if (p < blockcnt) {
            int b = bstage[p];
            ebuf[gbase[b] + p] = stage[p];
        }
    }
}

// ---- per-bucket counting sort (static bases; wave-shuffle scan, 4 barriers) ----
__global__ __launch_bounds__(256) void k_sort(const u32* __restrict__ ebuf, const int* __restrict__ gcur,
                                              int* __restrict__ csrc, int* __restrict__ deg,
                                              int* __restrict__ rowp) {
    __shared__ int degL[256];
    __shared__ int curL[256];
    __shared__ int wsum[4];
    int t = threadIdx.x;
    int lane = t & 63, wv = t >> 6;
    int b = blockIdx.x;
    int bs = b * CAP;
    int be = bs + gcur[b * 16];
    degL[t] = 0;
    __syncthreads();
    for (int e = bs + t; e < be; e += 256)
        atomicAdd(&degL[ebuf[e] >> 17], 1);
    __syncthreads();
    int myDeg = degL[t];
    int inc = myDeg;
#pragma unroll
    for (int off = 1; off < 64; off <<= 1) {
        int u = __shfl_up(inc, off, 64);
        if (lane >= off) inc += u;
    }
    if (lane == 63) wsum[wv] = inc;
    __syncthreads();
    int pre = 0;
    for (int i = 0; i < wv; i++) pre += wsum[i];
    int excl = inc + pre - myDeg;
    int node = (b << 8) + t;       // < 100096; deg=0 for node >= N_N
    deg[node] = myDeg;
    rowp[node] = bs + excl;
    curL[t] = bs + excl;
    __syncthreads();
    for (int e = bs + t; e < be; e += 256) {
        u32 w = ebuf[e];
        int p = atomicAdd(&curL[w >> 17], 1);
        csrc[p] = (int)(w & 0x1FFFFu);
    }
}

// ---- layer 1: gather (8 lanes/edge, unroll-2) + MFMA matmul; persists the
// 32-wide z-rows (As) to zb so k_agg can recompute h1 from a 64B gather ----
__global__ __launch_bounds__(256) void k_layer1(const u16* __restrict__ xpb,
                                                const int* __restrict__ rowp, const int* __restrict__ deg,
                                                const int* __restrict__ csrc,
                                                const u16* __restrict__ w1cat, const float* __restrict__ b1,
                                                u16* __restrict__ h1b, u16* __restrict__ zb) {
    __shared__ u16 As[16][32];       // [node][k]: k0..15 = mean(xp) (14,15=0), k16..31 = own row
    __shared__ u16 outS[16][256];    // D staging for coalesced writeout
    int tid = threadIdx.x;
    int wave = tid >> 6, lane = tid & 63;
    int fp = lane & 7;          // feature pair 0..7
    int eg = lane >> 3;         // edge group 0..7
    if (blockIdx.x == 0 && tid < 16)   // zero row at ZROW for k_agg's branchless tails
        *(u32*)(zb + (size_t)ZROW * 32 + tid * 2) = 0;
#pragma unroll
    for (int nn = 0; nn < 4; nn++) {
        int s = wave * 4 + nn;
        int node = blockIdx.x * 16 + s;     // grid covers exactly N_N
        int st = rowp[node], dg = deg[node];
        int end = st + dg;
        float a0 = 0.f, a1 = 0.f, b0 = 0.f, b1v = 0.f;
        int e = st + eg;
        for (; e + 8 < end; e += 16) {      // unroll-2: both csrc loads independent
            int nb1 = csrc[e];
            int nb2 = csrc[e + 8];
            u32 v1 = *(const u32*)(xpb + (size_t)nb1 * 16 + fp * 2);
            u32 v2 = *(const u32*)(xpb + (size_t)nb2 * 16 + fp * 2);
            a0 += __uint_as_float(v1 << 16);
            a1 += __uint_as_float(v1 & 0xFFFF0000u);
            b0 += __uint_as_float(v2 << 16);
            b1v += __uint_as_float(v2 & 0xFFFF0000u);
        }
        if (e < end) {
            int nb = csrc[e];
            u32 v = *(const u32*)(xpb + (size_t)nb * 16 + fp * 2);
            a0 += __uint_as_float(v << 16);
            a1 += __uint_as_float(v & 0xFFFF0000u);
        }
        a0 += b0; a1 += b1v;
        if (eg == 1) {   // own row is already bf16: copy pair directly (k 16..31)
            *(u32*)&As[s][16 + fp * 2] = *(const u32*)(xpb + (size_t)node * 16 + fp * 2);
        }
#pragma unroll
        for (int off = 32; off >= 8; off >>= 1) {
            a0 += __shfl_down(a0, off);
            a1 += __shfl_down(a1, off);
        }
        if (eg == 0) {
            float inv = 1.f / (float)max(dg, 1);
            *(u32*)&As[s][fp * 2] = f2b(a0 * inv) | (f2b(a1 * inv) << 16);
        }
    }
    __syncthreads();
    // persist z-rows: thread t -> node t>>4, u32 pair t&15 (coalesced 1KB/block)
    {
        int s = tid >> 4, kp = tid & 15;
        *(u32*)(zb + (size_t)(blockIdx.x * 16 + s) * 32 + kp * 2) = *(const u32*)&As[s][kp * 2];
    }
    // ---- MFMA phase: wave w covers output feats [w*64, w*64+64) as 4 16x16 tiles ----
    int quad = lane >> 4, m16 = lane & 15;
    bf16x8 afrag = *(const bf16x8*)&As[m16][quad * 8];
#pragma unroll
    for (int u = 0; u < 4; u++) {
        int feat = wave * 64 + u * 16 + m16;
        bf16x8 bfrag = *(const bf16x8*)(w1cat + (size_t)feat * 32 + quad * 8);
        f32x4 d = {0.f, 0.f, 0.f, 0.f};
        d = __builtin_amdgcn_mfma_f32_16x16x32_bf16(afrag, bfrag, d, 0, 0, 0);
        float bj = b1[feat];
#pragma unroll
        for (int i = 0; i < 4; i++) {
            int row = quad * 4 + i;          // node within tile
            outS[row][feat] = (u16)f2b(fmaxf(d[i] + bj, 0.f));
        }
    }
    __syncthreads();
    // ---- coalesced writeout: thread t -> node t>>4, 32B chunk t&15 ----
    int r = tid >> 4, c = tid & 15;
    uint4* dst = (uint4*)(h1b + ((size_t)(blockIdx.x * 16 + r)) * HID + c * 16);
    dst[0] = *(const uint4*)&outS[r][c * 16];
    dst[1] = *(const uint4*)&outS[r][c * 16 + 8];
}

// ---- layer-2 mean aggregation, RECOMPUTE v4 (resubmit: R4 bench was an
// infra failure — container acquisition died twice; kernel never ran) ----
// R3 post-mortem: spills persisted (WRITE 504MB). Root cause: per chunk the
// compiler keeps 16 B-frags (64 VGPR, LICM-hoisted from LDS) AND 16 in-flight
// f32x4 MFMA temporaries (64 VGPR) -> ~190 live vs the 128 cap. Fix: halve the
// per-wave working set. TWO waves per node, each owning 128 feats (8 u-tiles):
// B 32 + d-temps <=32 + acc 8 + nbb 8 + af/afn 8 + addr ~25 = ~110 < 128.
// B-frags load straight from global w1cat (16KB, L2-broadcast; no LDS stage).
// Paired waves share the block -> sibling zb gathers hit L1. #pragma unroll 1
// on node/chunk loops prevents cross-iteration pressure spikes.
// Branchless ZROW tail + relu algebra (proven R1-R3):
//   relu(g+b) = max(g,-b)+b; padded rows (z=0) contribute relu(-b)
//   => sum_valid relu = acc - nmask*relu(-b) + dg*b
__global__ __launch_bounds__(256, 4) void k_agg(const u16* __restrict__ zb, const int* __restrict__ rowp,
                                                const int* __restrict__ deg, const int* __restrict__ csrc,
                                                const u16* __restrict__ w1cat, const float* __restrict__ b1,
                                                u16* __restrict__ mean1b) {
    __shared__ u16 outW[4][128];     // per-wave writeout staging (256B each)
    int tid = threadIdx.x;
    int wv = tid >> 6, lane = tid & 63;
    int quad = lane >> 4, m16 = lane & 15;
    int half = wv & 1;               // which 128 feats this wave owns
    int slot = wv >> 1;              // which node-stream (2 per block)
    // B-frags + neg-bias for this wave's 8 feat-tiles, direct from global (L2)
    bf16x8 bfrag[8];
    float nbb[8];
#pragma unroll
    for (int u = 0; u < 8; u++) {
        int feat = half * 128 + u * 16 + m16;
        bfrag[u] = *(const bf16x8*)(w1cat + (size_t)feat * 32 + quad * 8);
        nbb[u] = -b1[feat];
    }
    int nbase = (blockIdx.x * 2 + slot) * NPW;   // grid covers exactly N_N
#pragma unroll 1
    for (int j = 0; j < NPW; j++) {
        int node = nbase + j;
        int st = rowp[node], dg = deg[node];     // wave-uniform
        int end = st + dg;
        float acc[8] = {};
        int e0 = st + m16;
        int nb = (e0 < end) ? csrc[e0] : ZROW;
        bf16x8 af = *(const bf16x8*)(zb + (size_t)nb * 32 + quad * 8);
#pragma unroll 1
        for (int cb = 0; cb < dg; cb += 16) {
            // prefetch next chunk's A-frag (zero-row load past the end)
            int e2 = st + cb + 16 + m16;
            int nb2 = (e2 < end) ? csrc[e2] : ZROW;
            bf16x8 afn = *(const bf16x8*)(zb + (size_t)nb2 * 32 + quad * 8);
#pragma unroll
            for (int u = 0; u < 8; u++) {
                f32x4 d = {0.f, 0.f, 0.f, 0.f};
                d = __builtin_amdgcn_mfma_f32_16x16x32_bf16(af, bfrag[u], d, 0, 0, 0);
                acc[u] += (fmaxf(d[0], nbb[u]) + fmaxf(d[1], nbb[u])) +
                          (fmaxf(d[2], nbb[u]) + fmaxf(d[3], nbb[u]));
            }
            af = afn;
        }
        int nch = (dg + 15) >> 4;
        float inv = 1.f / (float)max(dg, 1);
        float fdg = (float)dg;
        float fnm = (float)(nch * 16 - dg);
#pragma unroll
        for (int u = 0; u < 8; u++) {
            float a = acc[u];
            a += __shfl_down(a, 32);     // quads {0,1}+{2,3}
            a += __shfl_down(a, 16);     // + quad 1
            float rnb = fmaxf(nbb[u], 0.f);
            a = fmaf(fdg, -nbb[u], a);   // + dg*b
            a = fmaf(-fnm, rnb, a);      // - nmask*relu(-b)
            if (quad == 0) outW[wv][u * 16 + m16] = (u16)f2b(a * inv);
        }
        // same-wave LDS dependency: compiler orders via lgkmcnt; no barrier needed
        if (lane < 16)
            *(uint4*)(mean1b + (size_t)node * HID + half * 128 + (size_t)lane * 8) =
                *(const uint4*)&outW[wv][lane * 8];
    }
}

// ---- layer 2 (BM=128, Bs double-kt — ~24 us): direct-global A-frags + register
// prefetch; fused relu + Wout-dot + pool atomic ----
__global__ __launch_bounds__(256, 2) void k_layer2(const u16* __restrict__ mean1b, const u16* __restrict__ h1b,
                                                   const u16* __restrict__ wcat, const float* __restrict__ b2,
                                                   const int* __restrict__ batch, const float* __restrict__ Wout,
                                                   float* __restrict__ outsum) {
    __shared__ u16 Bs[2][256][40];
    int tid = threadIdx.x;
    int wave = tid >> 6, lane = tid & 63;
    int quad = lane >> 4, m16 = lane & 15;
    int bm = blockIdx.x;
    const size_t r0 = (size_t)(bm * 128 + wave * 32 + m16) * HID + quad * 8;
    const size_t r1 = r0 + 16 * HID;
    f32x4 acc[2][16] = {};
    uint4 a0 = *(const uint4*)(mean1b + r0);
    uint4 a1 = *(const uint4*)(mean1b + r1);
    for (int kt2 = 0; kt2 < 8; kt2++) {
        __syncthreads();
#pragma unroll
        for (int h = 0; h < 2; h++) {
            int kt = kt2 * 2 + h;
#pragma unroll
            for (int i = 0; i < 4; i++) {
                int cidx = tid + 256 * i;
                int n = cidx >> 2, kc = cidx & 3;
                *(uint4*)&Bs[h][n][kc * 8] =
                    *(const uint4*)(wcat + (size_t)n * 512 + kt * 32 + kc * 8);
            }
        }
        __syncthreads();
#pragma unroll
        for (int h = 0; h < 2; h++) {
            int kt = kt2 * 2 + h;
            uint4 cur0 = a0, cur1 = a1;
            if (kt < 15) {
                int kg = (kt + 1) * 32;
                const u16* An = (kg < 256) ? (mean1b + kg) : (h1b + (kg - 256));
                a0 = *(const uint4*)(An + r0);
                a1 = *(const uint4*)(An + r1);
            }
            bf16x8 af0 = __builtin_bit_cast(bf16x8, cur0);
            bf16x8 af1 = __builtin_bit_cast(bf16x8, cur1);
#pragma unroll
            for (int u = 0; u < 16; u++) {
                bf16x8 bf = *(const bf16x8*)&Bs[h][u * 16 + m16][quad * 8];
                acc[0][u] = __builtin_amdgcn_mfma_f32_16x16x32_bf16(af0, bf, acc[0][u], 0, 0, 0);
                acc[1][u] = __builtin_amdgcn_mfma_f32_16x16x32_bf16(af1, bf, acc[1][u], 0, 0, 0);
            }
        }
    }
    float wo[16], bb[16];
#pragma unroll
    for (int u = 0; u < 16; u++) { int col = u * 16 + m16; wo[u] = Wout[col]; bb[u] = b2[col]; }
#pragma unroll
    for (int t = 0; t < 2; t++) {
#pragma unroll
        for (int i = 0; i < 4; i++) {
            float p = 0.f;
#pragma unroll
            for (int u = 0; u < 16; u++)
                p = fmaf(fmaxf(acc[t][u][i] + bb[u], 0.f), wo[u], p);
#pragma unroll
            for (int off = 8; off > 0; off >>= 1) p += __shfl_down(p, off, 16);
            int row = bm * 128 + wave * 32 + t * 16 + quad * 4 + i;
            if (m16 == 0 && row < N_N) atomicAdd(&outsum[batch[row]], p);
        }
    }
}

// ---- output head ----
__global__ __launch_bounds__(256) void k_out(const float* __restrict__ outsum, const float* __restrict__ gcnt,
                                             const float* __restrict__ bout, float* __restrict__ out) {
    int g = blockIdx.x * 256 + threadIdx.x;
    if (g < N_G) out[g] = outsum[g] / fmaxf(gcnt[g], 1.f) + bout[0];
}

extern "C" void kernel_launch(void* const* d_in, const int* in_sizes, int n_in,
                              void* d_out, int out_size, void* d_ws, size_t ws_size,
                              hipStream_t stream) {
    const float* x    = (const float*)d_in[0];
    const float* pos  = (const float*)d_in[1];
    const int*   ei   = (const int*)d_in[2];
    const int*   batch= (const int*)d_in[3];
    const float* W1l  = (const float*)d_in[4];
    const float* b1   = (const float*)d_in[5];
    const float* W1r  = (const float*)d_in[6];
    const float* W2l  = (const float*)d_in[7];
    const float* b2   = (const float*)d_in[8];
    const float* W2r  = (const float*)d_in[9];
    const float* Wout = (const float*)d_in[10];
    const float* bout = (const float*)d_in[11];
    float* out = (float*)d_out;
    float* ws  = (float*)d_ws;

    float* outs  = ws + OFF_OUTS;
    int*   gcur  = (int*)(ws + OFF_GCUR);
    float* gcnt  = ws + OFF_GCNT;
    int*   rowp  = (int*)(ws + OFF_ROWP);
    int*   deg   = (int*)(ws + OFF_DEG);
    u32*   ebuf  = (u32*)(ws + OFF_EBUF);
    int*   csrc  = (int*)(ws + OFF_CSRC);
    u16*   h1b   = (u16*)(ws + OFF_H1B);
    u16*   wcat  = (u16*)(ws + OFF_WCAT);
    u16*   xpb   = (u16*)(ws + OFF_XP);
    u16*   mean1b= (u16*)(ws + OFF_MEAN1B);
    u16*   w1cat = (u16*)(ws + OFF_W1CAT);
    u16*   zb    = (u16*)ebuf;      // ebuf is dead after k_sort; reuse for z-rows

    hipMemsetAsync(d_ws, 0, ZERO_BYTES, stream);
    k_bfill_prep<<<NFB + PREP_BLKS, 512, 0, stream>>>(
        ei, gcur, ebuf, x, pos, batch, W2l, W2r, W1l, W1r, xpb, gcnt, wcat, w1cat);
    k_sort  <<<NBUK, 256, 0, stream>>>(ebuf, gcur, csrc, deg, rowp);
    k_layer1<<<N_N / 16, 256, 0, stream>>>(xpb, rowp, deg, csrc, w1cat, b1, h1b, zb);
    k_agg   <<<N_N / (2 * NPW), 256, 0, stream>>>(zb, rowp, deg, csrc, w1cat, b1, mean1b);
    k_layer2<<<(N_N + 127) / 128, 256, 0, stream>>>(mean1b, h1b, wcat, b2, batch, Wout, outs);
    k_out   <<<(N_G + 255) / 256, 256, 0, stream>>>(outs, gcnt, bout, out);
}

// Round 6
// 325.821 us; speedup vs baseline: 2.0248x; 1.0661x over previous
//
#include <hip/hip_runtime.h>

#define N_N 100000
#define N_E 1600000
#define N_G 5000
#define HID 256
#define IND 14

#define NBUK 391      // buckets: dst>>8, 256 nodes each (391*256 = 100096)
#define CAP 5120      // static per-bucket capacity (E[cnt]=4096, sigma~64; +16 sigma)
#define CH3 8192      // edges per binning block (512 threads)
#define NFB 196       // ceil(N_E/CH3)

typedef __bf16 bf16x8 __attribute__((ext_vector_type(8)));
typedef float f32x4 __attribute__((ext_vector_type(4)));
typedef unsigned short u16;
typedef unsigned int u32;

// ---- workspace layout (units of 4 bytes) ----
constexpr size_t OFF_OUTS  = 0;          // float[5120]   (zeroed)
constexpr size_t OFF_GCUR  = 5120;       // int[391*16]   (zeroed, 64B-padded cursors)
constexpr size_t ZERO_END  = 11520;
constexpr size_t ZERO_BYTES = ZERO_END * 4;
constexpr size_t OFF_GCNT  = 11520;      // float[5120] (fully written)
constexpr size_t OFF_ROWP  = 16640;      // int[100096]
constexpr size_t OFF_DEG   = 116736;     // int[100096]
constexpr size_t OFF_EBUF  = 216832;     // u32[391*5120]
constexpr size_t OFF_CSRC  = 2218752;    // int[391*5120]
constexpr size_t OFF_H1B   = 4220672;    // bf16[100096*256] -> ends 17032960
constexpr size_t OFF_WCAT  = 17032960;   // bf16[256*512]    -> ends 17098496
constexpr size_t OFF_XP    = 17098496;   // bf16[N*16]       -> ends 17898496
constexpr size_t OFF_MEAN1B= 17898496;   // bf16[100096*256] -> ends 30710784
constexpr size_t OFF_W1CAT = 30710784;   // bf16[256*32]     -> ends 30714880
// end = 30714880 floats ~= 123 MB

__device__ __forceinline__ u32 f2b(float f) {
    u32 u = __float_as_uint(f);
    u32 r = u + 0x7FFFu + ((u >> 16) & 1u);
    return r >> 16;
}

#define ADD8(acc, v) do { \
    acc[0] += __uint_as_float(v.x << 16); \
    acc[1] += __uint_as_float(v.x & 0xFFFF0000u); \
    acc[2] += __uint_as_float(v.y << 16); \
    acc[3] += __uint_as_float(v.y & 0xFFFF0000u); \
    acc[4] += __uint_as_float(v.z << 16); \
    acc[5] += __uint_as_float(v.z & 0xFFFF0000u); \
    acc[6] += __uint_as_float(v.w << 16); \
    acc[7] += __uint_as_float(v.w & 0xFFFF0000u); \
} while (0)

// ---- MERGED binning + prep; scan via wave-shuffle (2 barriers vs 18) ----
#define PACK_N (N_N * 16)
#define WCAT_N (256 * 512)
#define W1CAT_N (256 * 32)
#define PREP_TOT (PACK_N + WCAT_N + W1CAT_N + N_G)
#define PREP_BLKS ((PREP_TOT + 511) / 512)      // 3407
__global__ __launch_bounds__(512) void k_bfill_prep(const int* __restrict__ ei, int* __restrict__ gcur,
                                                    u32* __restrict__ ebuf,
                                                    const float* __restrict__ x, const float* __restrict__ pos,
                                                    const int* __restrict__ batch,
                                                    const float* __restrict__ W2l, const float* __restrict__ W2r,
                                                    const float* __restrict__ W1l, const float* __restrict__ W1r,
                                                    u16* __restrict__ xpb, float* __restrict__ gcnt,
                                                    u16* __restrict__ wcat, u16* __restrict__ w1cat) {
    __shared__ int hist[NBUK];
    __shared__ int lcur[NBUK];
    __shared__ int gbase[NBUK];
    __shared__ int wsum[8];
    __shared__ u32 stage[CH3];
    __shared__ u16 bstage[CH3];
    int t = threadIdx.x;
    if (blockIdx.x >= NFB) {
        int idx = (blockIdx.x - NFB) * 512 + t;
        if (idx < PACK_N) {
            int n = idx >> 4, f = idx & 15;
            float v = 0.f;
            if (f < 11) v = x[n * 11 + f];
            else if (f < 14) v = pos[n * 3 + (f - 11)];
            xpb[idx] = (u16)f2b(v);
        } else if (idx < PACK_N + WCAT_N) {
            int i2 = idx - PACK_N;
            int n = i2 >> 9, k = i2 & 511;
            float v = (k < 256) ? W2l[k * HID + n] : W2r[(k - 256) * HID + n];
            wcat[(size_t)n * 512 + k] = (u16)f2b(v);
        } else if (idx < PACK_N + WCAT_N + W1CAT_N) {
            int i2 = idx - PACK_N - WCAT_N;
            int n = i2 >> 5, k = i2 & 31;
            float v = 0.f;
            if (k < IND) v = W1l[k * HID + n];
            else if (k >= 16 && k < 16 + IND) v = W1r[(k - 16) * HID + n];
            w1cat[(size_t)n * 32 + k] = (u16)f2b(v);
        } else if (idx < PREP_TOT) {
            int g = idx - PACK_N - WCAT_N - W1CAT_N;
            int lo = 0, hi = N_N;
            while (lo < hi) { int mid = (lo + hi) >> 1; if (batch[mid] < g) lo = mid + 1; else hi = mid; }
            int lo2 = lo, hi2 = N_N;
            while (lo2 < hi2) { int mid = (lo2 + hi2) >> 1; if (batch[mid] < g + 1) lo2 = mid + 1; else hi2 = mid; }
            gcnt[g] = (float)(lo2 - lo);
        }
        return;
    }
    int lane = t & 63, wv = t >> 6;
    int base = blockIdx.x * CH3;
    for (int i = t; i < NBUK; i += 512) hist[i] = 0;
    __syncthreads();
#pragma unroll
    for (int i = 0; i < 16; i++) {
        int e = base + i * 512 + t;
        if (e < N_E) atomicAdd(&hist[ei[N_E + e] >> 8], 1);
    }
    __syncthreads();
    // wave-shuffle inclusive scan of hist over 512 lanes
    int v = (t < NBUK) ? hist[t] : 0;
    int inc = v;
#pragma unroll
    for (int off = 1; off < 64; off <<= 1) {
        int u = __shfl_up(inc, off, 64);
        if (lane >= off) inc += u;
    }
    if (lane == 63) wsum[wv] = inc;
    __syncthreads();
    int pre = 0;
    for (int i = 0; i < wv; i++) pre += wsum[i];
    int inclusive = inc + pre;
    int excl = inclusive - v;                 // exclusive base within stage (reg-saved)
    if (t < NBUK) lcur[t] = excl;
    int blockcnt = 0;
#pragma unroll
    for (int i = 0; i < 8; i++) blockcnt += wsum[i];
    __syncthreads();
#pragma unroll
    for (int i = 0; i < 16; i++) {
        int e = base + i * 512 + t;
        if (e < N_E) {
            int d = ei[N_E + e];
            int s = ei[e];
            int b = d >> 8;
            int p = atomicAdd(&lcur[b], 1);
            stage[p] = (u32)s | ((u32)(d & 255) << 17);
            bstage[p] = (u16)b;
        }
    }
    __syncthreads();
    if (t < NBUK) {
        int c = hist[t];
        int o = c ? atomicAdd(&gcur[t * 16], c) : 0;
        gbase[t] = t * CAP + o - excl;        // so global = gbase[b] + p
    }
    __syncthreads();
#pragma unroll
    for (int i = 0; i < 16; i++) {
        int p = i * 512 + t;
        if (p < blockcnt) {
            int b = bstage[p];
            ebuf[gbase[b] + p] = stage[p];
        }
    }
}

// ---- per-bucket counting sort (static bases; wave-shuffle scan, 4 barriers) ----
__global__ __launch_bounds__(256) void k_sort(const u32* __restrict__ ebuf, const int* __restrict__ gcur,
                                              int* __restrict__ csrc, int* __restrict__ deg,
                                              int* __restrict__ rowp) {
    __shared__ int degL[256];
    __shared__ int curL[256];
    __shared__ int wsum[4];
    int t = threadIdx.x;
    int lane = t & 63, wv = t >> 6;
    int b = blockIdx.x;
    int bs = b * CAP;
    int be = bs + gcur[b * 16];
    degL[t] = 0;
    __syncthreads();
    for (int e = bs + t; e < be; e += 256)
        atomicAdd(&degL[ebuf[e] >> 17], 1);
    __syncthreads();
    int myDeg = degL[t];
    int inc = myDeg;
#pragma unroll
    for (int off = 1; off < 64; off <<= 1) {
        int u = __shfl_up(inc, off, 64);
        if (lane >= off) inc += u;
    }
    if (lane == 63) wsum[wv] = inc;
    __syncthreads();
    int pre = 0;
    for (int i = 0; i < wv; i++) pre += wsum[i];
    int excl = inc + pre - myDeg;
    int node = (b << 8) + t;       // < 100096; deg=0 for node >= N_N
    deg[node] = myDeg;
    rowp[node] = bs + excl;
    curL[t] = bs + excl;
    __syncthreads();
    for (int e = bs + t; e < be; e += 256) {
        u32 w = ebuf[e];
        int p = atomicAdd(&curL[w >> 17], 1);
        csrc[p] = (int)(w & 0x1FFFFu);
    }
}

// ---- layer 1: gather (8 lanes/edge, unroll-2) + MFMA matmul ----
__global__ __launch_bounds__(256) void k_layer1(const u16* __restrict__ xpb,
                                                const int* __restrict__ rowp, const int* __restrict__ deg,
                                                const int* __restrict__ csrc,
                                                const u16* __restrict__ w1cat, const float* __restrict__ b1,
                                                u16* __restrict__ h1b) {
    __shared__ u16 As[16][32];       // [node][k]: k0..15 = mean(xp) (14,15=0), k16..31 = own row
    __shared__ u16 outS[16][256];    // D staging for coalesced writeout
    int tid = threadIdx.x;
    int wave = tid >> 6, lane = tid & 63;
    int fp = lane & 7;          // feature pair 0..7
    int eg = lane >> 3;         // edge group 0..7
#pragma unroll
    for (int nn = 0; nn < 4; nn++) {
        int s = wave * 4 + nn;
        int node = blockIdx.x * 16 + s;     // grid covers exactly N_N
        int st = rowp[node], dg = deg[node];
        int end = st + dg;
        float a0 = 0.f, a1 = 0.f, b0 = 0.f, b1v = 0.f;
        int e = st + eg;
        for (; e + 8 < end; e += 16) {      // unroll-2: both csrc loads independent
            int nb1 = csrc[e];
            int nb2 = csrc[e + 8];
            u32 v1 = *(const u32*)(xpb + (size_t)nb1 * 16 + fp * 2);
            u32 v2 = *(const u32*)(xpb + (size_t)nb2 * 16 + fp * 2);
            a0 += __uint_as_float(v1 << 16);
            a1 += __uint_as_float(v1 & 0xFFFF0000u);
            b0 += __uint_as_float(v2 << 16);
            b1v += __uint_as_float(v2 & 0xFFFF0000u);
        }
        if (e < end) {
            int nb = csrc[e];
            u32 v = *(const u32*)(xpb + (size_t)nb * 16 + fp * 2);
            a0 += __uint_as_float(v << 16);
            a1 += __uint_as_float(v & 0xFFFF0000u);
        }
        a0 += b0; a1 += b1v;
        if (eg == 1) {   // own row is already bf16: copy pair directly (k 16..31)
            *(u32*)&As[s][16 + fp * 2] = *(const u32*)(xpb + (size_t)node * 16 + fp * 2);
        }
#pragma unroll
        for (int off = 32; off >= 8; off >>= 1) {
            a0 += __shfl_down(a0, off);
            a1 += __shfl_down(a1, off);
        }
        if (eg == 0) {
            float inv = 1.f / (float)max(dg, 1);
            *(u32*)&As[s][fp * 2] = f2b(a0 * inv) | (f2b(a1 * inv) << 16);
        }
    }
    __syncthreads();
    // ---- MFMA phase: wave w covers output feats [w*64, w*64+64) as 4 16x16 tiles ----
    int quad = lane >> 4, m16 = lane & 15;
    bf16x8 afrag = *(const bf16x8*)&As[m16][quad * 8];
#pragma unroll
    for (int u = 0; u < 4; u++) {
        int feat = wave * 64 + u * 16 + m16;
        bf16x8 bfrag = *(const bf16x8*)(w1cat + (size_t)feat * 32 + quad * 8);
        f32x4 d = {0.f, 0.f, 0.f, 0.f};
        d = __builtin_amdgcn_mfma_f32_16x16x32_bf16(afrag, bfrag, d, 0, 0, 0);
        float bj = b1[feat];
#pragma unroll
        for (int i = 0; i < 4; i++) {
            int row = quad * 4 + i;          // node within tile
            outS[row][feat] = (u16)f2b(fmaxf(d[i] + bj, 0.f));
        }
    }
    __syncthreads();
    // ---- coalesced writeout: thread t -> node t>>4, 32B chunk t&15 ----
    int r = tid >> 4, c = tid & 15;
    uint4* dst = (uint4*)(h1b + ((size_t)(blockIdx.x * 16 + r)) * HID + c * 16);
    dst[0] = *(const uint4*)&outS[r][c * 16];
    dst[1] = *(const uint4*)&outS[r][c * 16 + 8];
}

// ---- layer-2 mean aggregation: 1 wave/node, 4 rows in flight (pinned at the
// ~3.9 TB/s scattered-gather service wall; R7/R10/R16 of the original session
// and the R0-R5 recompute arc of this session all falsified alternatives:
// recompute-from-z was latency-bound at 145us vs this kernel's 111us) ----
__global__ __launch_bounds__(256) void k_agg(const u16* __restrict__ h1b, const int* __restrict__ rowp,
                                             const int* __restrict__ deg, const int* __restrict__ csrc,
                                             u16* __restrict__ mean1b) {
    int tid = threadIdx.x;
    int node = blockIdx.x * 4 + (tid >> 6);
    int lane = tid & 63;
    int half = lane >> 5, l32 = lane & 31;
    int st = rowp[node], dg = deg[node];
    int end = st + dg;
    const size_t roff = (size_t)l32 * 8;
    float accA[8] = {}, accB[8] = {};
    int e = st + half;
    for (; e + 2 < end; e += 4) {
        int nb1 = csrc[e];
        int nb2 = csrc[e + 2];
        uint4 v1 = *(const uint4*)(h1b + (size_t)nb1 * HID + roff);
        uint4 v2 = *(const uint4*)(h1b + (size_t)nb2 * HID + roff);
        ADD8(accA, v1);
        ADD8(accB, v2);
    }
    if (e < end) {
        int nb = csrc[e];
        uint4 v = *(const uint4*)(h1b + (size_t)nb * HID + roff);
        ADD8(accA, v);
    }
    float acc[8];
#pragma unroll
    for (int j = 0; j < 8; j++) acc[j] = accA[j] + accB[j];
#pragma unroll
    for (int j = 0; j < 8; j++) acc[j] += __shfl_down(acc[j], 32);
    if (lane < 32) {
        float inv = 1.f / (float)max(dg, 1);
        uint4 o;
        o.x = f2b(acc[0] * inv) | (f2b(acc[1] * inv) << 16);
        o.y = f2b(acc[2] * inv) | (f2b(acc[3] * inv) << 16);
        o.z = f2b(acc[4] * inv) | (f2b(acc[5] * inv) << 16);
        o.w = f2b(acc[6] * inv) | (f2b(acc[7] * inv) << 16);
        *(uint4*)(mean1b + (size_t)node * HID + roff) = o;
    }
}

// ---- layer 2 (BM=128, Bs double-kt — ~24 us): direct-global A-frags + register
// prefetch; fused relu + Wout-dot + pool atomic ----
__global__ __launch_bounds__(256, 2) void k_layer2(const u16* __restrict__ mean1b, const u16* __restrict__ h1b,
                                                   const u16* __restrict__ wcat, const float* __restrict__ b2,
                                                   const int* __restrict__ batch, const float* __restrict__ Wout,
                                                   float* __restrict__ outsum) {
    __shared__ u16 Bs[2][256][40];
    int tid = threadIdx.x;
    int wave = tid >> 6, lane = tid & 63;
    int quad = lane >> 4, m16 = lane & 15;
    int bm = blockIdx.x;
    const size_t r0 = (size_t)(bm * 128 + wave * 32 + m16) * HID + quad * 8;
    const size_t r1 = r0 + 16 * HID;
    f32x4 acc[2][16] = {};
    uint4 a0 = *(const uint4*)(mean1b + r0);
    uint4 a1 = *(const uint4*)(mean1b + r1);
    for (int kt2 = 0; kt2 < 8; kt2++) {
        __syncthreads();
#pragma unroll
        for (int h = 0; h < 2; h++) {
            int kt = kt2 * 2 + h;
#pragma unroll
            for (int i = 0; i < 4; i++) {
                int cidx = tid + 256 * i;
                int n = cidx >> 2, kc = cidx & 3;
                *(uint4*)&Bs[h][n][kc * 8] =
                    *(const uint4*)(wcat + (size_t)n * 512 + kt * 32 + kc * 8);
            }
        }
        __syncthreads();
#pragma unroll
        for (int h = 0; h < 2; h++) {
            int kt = kt2 * 2 + h;
            uint4 cur0 = a0, cur1 = a1;
            if (kt < 15) {
                int kg = (kt + 1) * 32;
                const u16* An = (kg < 256) ? (mean1b + kg) : (h1b + (kg - 256));
                a0 = *(const uint4*)(An + r0);
                a1 = *(const uint4*)(An + r1);
            }
            bf16x8 af0 = __builtin_bit_cast(bf16x8, cur0);
            bf16x8 af1 = __builtin_bit_cast(bf16x8, cur1);
#pragma unroll
            for (int u = 0; u < 16; u++) {
                bf16x8 bf = *(const bf16x8*)&Bs[h][u * 16 + m16][quad * 8];
                acc[0][u] = __builtin_amdgcn_mfma_f32_16x16x32_bf16(af0, bf, acc[0][u], 0, 0, 0);
                acc[1][u] = __builtin_amdgcn_mfma_f32_16x16x32_bf16(af1, bf, acc[1][u], 0, 0, 0);
            }
        }
    }
    float wo[16], bb[16];
#pragma unroll
    for (int u = 0; u < 16; u++) { int col = u * 16 + m16; wo[u] = Wout[col]; bb[u] = b2[col]; }
#pragma unroll
    for (int t = 0; t < 2; t++) {
#pragma unroll
        for (int i = 0; i < 4; i++) {
            float p = 0.f;
#pragma unroll
            for (int u = 0; u < 16; u++)
                p = fmaf(fmaxf(acc[t][u][i] + bb[u], 0.f), wo[u], p);
#pragma unroll
            for (int off = 8; off > 0; off >>= 1) p += __shfl_down(p, off, 16);
            int row = bm * 128 + wave * 32 + t * 16 + quad * 4 + i;
            if (m16 == 0 && row < N_N) atomicAdd(&outsum[batch[row]], p);
        }
    }
}

// ---- output head ----
__global__ __launch_bounds__(256) void k_out(const float* __restrict__ outsum, const float* __restrict__ gcnt,
                                             const float* __restrict__ bout, float* __restrict__ out) {
    int g = blockIdx.x * 256 + threadIdx.x;
    if (g < N_G) out[g] = outsum[g] / fmaxf(gcnt[g], 1.f) + bout[0];
}

extern "C" void kernel_launch(void* const* d_in, const int* in_sizes, int n_in,
                              void* d_out, int out_size, void* d_ws, size_t ws_size,
                              hipStream_t stream) {
    const float* x    = (const float*)d_in[0];
    const float* pos  = (const float*)d_in[1];
    const int*   ei   = (const int*)d_in[2];
    const int*   batch= (const int*)d_in[3];
    const float* W1l  = (const float*)d_in[4];
    const float* b1   = (const float*)d_in[5];
    const float* W1r  = (const float*)d_in[6];
    const float* W2l  = (const float*)d_in[7];
    const float* b2   = (const float*)d_in[8];
    const float* W2r  = (const float*)d_in[9];
    const float* Wout = (const float*)d_in[10];
    const float* bout = (const float*)d_in[11];
    float* out = (float*)d_out;
    float* ws  = (float*)d_ws;

    float* outs  = ws + OFF_OUTS;
    int*   gcur  = (int*)(ws + OFF_GCUR);
    float* gcnt  = ws + OFF_GCNT;
    int*   rowp  = (int*)(ws + OFF_ROWP);
    int*   deg   = (int*)(ws + OFF_DEG);
    u32*   ebuf  = (u32*)(ws + OFF_EBUF);
    int*   csrc  = (int*)(ws + OFF_CSRC);
    u16*   h1b   = (u16*)(ws + OFF_H1B);
    u16*   wcat  = (u16*)(ws + OFF_WCAT);
    u16*   xpb   = (u16*)(ws + OFF_XP);
    u16*   mean1b= (u16*)(ws + OFF_MEAN1B);
    u16*   w1cat = (u16*)(ws + OFF_W1CAT);

    hipMemsetAsync(d_ws, 0, ZERO_BYTES, stream);
    k_bfill_prep<<<NFB + PREP_BLKS, 512, 0, stream>>>(
        ei, gcur, ebuf, x, pos, batch, W2l, W2r, W1l, W1r, xpb, gcnt, wcat, w1cat);
    k_sort  <<<NBUK, 256, 0, stream>>>(ebuf, gcur, csrc, deg, rowp);
    k_layer1<<<N_N / 16, 256, 0, stream>>>(xpb, rowp, deg, csrc, w1cat, b1, h1b);
    k_agg   <<<N_N / 4, 256, 0, stream>>>(h1b, rowp, deg, csrc, mean1b);
    k_layer2<<<(N_N + 127) / 128, 256, 0, stream>>>(mean1b, h1b, wcat, b2, batch, Wout, outs);
    k_out   <<<(N_G + 255) / 256, 256, 0, stream>>>(outs, gcnt, bout, out);
}